// Round 11
// baseline (909.057 us; speedup 1.0000x reference)
//
#include <hip/hip_runtime.h>
#include <algorithm>

#define DT_F 0.02f
#define INV_R (1.0f / 0.1125f)

typedef __attribute__((ext_vector_type(8))) short short8;
typedef __attribute__((ext_vector_type(4))) float float4v;

static inline int cdiv(int a, int b) { return (a + b - 1) / b; }

__device__ __forceinline__ float sgnf(float v) {
    return (v > 0.f) ? 1.f : ((v < 0.f) ? -1.f : 0.f);
}

__device__ __forceinline__ unsigned short f2bf(float f) {
    union { float f; unsigned u; } v; v.f = f;
    return (unsigned short)((v.u + 0x7fffu + ((v.u >> 16) & 1u)) >> 16);
}
__device__ __forceinline__ float bf2f(unsigned short h) {
    union { unsigned u; float f; } v; v.u = ((unsigned)h) << 16;
    return v.f;
}

// Exact port of reference ball_to_cube (f32).
__device__ __forceinline__ void ball_to_cube_dev(float x, float y, float z,
                                                 float& ox, float& oy, float& oz) {
    const float eps = 1e-12f;
    float sq = x * x + y * y + z * z;
    float nrm = sqrtf(sq + eps);
    float xy2 = x * x + y * y;
    bool cap = 1.25f * z * z > xy2;
    float s_cap = sqrtf(3.f * nrm / (nrm + fabsf(z) + eps));
    float s_side = nrm / sqrtf(xy2 + eps);
    float s = cap ? s_cap : s_side;
    float xc = x * s, yc = y * s;
    float zc = cap ? sgnf(z) * nrm : 1.5f * z;
    if (!(sq > eps)) { xc = 0.f; yc = 0.f; zc = 0.f; }
    float rxy = sqrtf(xc * xc + yc * yc + eps);
    bool xbig = fabsf(yc) <= fabsf(xc);
    float dx = (fabsf(xc) > eps) ? xc : 1.f;
    float dy = (fabsf(yc) > eps) ? yc : 1.f;
    const float c4pi = 1.27323954473516276f;  // 4/pi
    float tx = sgnf(xc) * rxy, ty = sgnf(yc) * rxy;
    float xq = xbig ? tx : ty * c4pi * atanf(xc / dy);
    float yq = xbig ? tx * c4pi * atanf(yc / dx) : ty;
    if (!(xc * xc + yc * yc > eps)) { xq = 0.f; yq = 0.f; }
    ox = xq; oy = yq; oz = zc;
}

__global__ void prep_kernel(const float* __restrict__ pos, const float* __restrict__ vel,
                            int n, float* __restrict__ pos2, float* __restrict__ fl) {
    int i = blockIdx.x * blockDim.x + threadIdx.x;
    if (i >= n) return;
    float v0 = vel[i * 3 + 0], v1 = vel[i * 3 + 1], v2 = vel[i * 3 + 2];
    float u0 = v0, u1 = v1 + DT_F * (-9.81f), u2 = v2;
    pos2[i * 3 + 0] = pos[i * 3 + 0] + DT_F * (u0 + v0) * 0.5f;
    pos2[i * 3 + 1] = pos[i * 3 + 1] + DT_F * (u1 + v1) * 0.5f;
    pos2[i * 3 + 2] = pos[i * 3 + 2] + DT_F * (u2 + v2) * 0.5f;
    fl[i * 4 + 0] = 1.f;
    fl[i * 4 + 1] = u0;
    fl[i * 4 + 2] = u1;
    fl[i * 4 + 3] = u2;
}

__global__ void row_ptr_kernel(const int* __restrict__ q_idx, int E, int nq,
                               int* __restrict__ row_ptr) {
    int q = blockIdx.x * blockDim.x + threadIdx.x;
    if (q > nq) return;
    int lo = 0, hi = E;
    while (lo < hi) {
        int mid = (lo + hi) >> 1;
        if (q_idx[mid] < q) lo = mid + 1; else hi = mid;
    }
    row_ptr[q] = lo;
}

// Per-edge geometry once; ix clamped to [0,2] => 8 distinct corners.
// Outputs: wgt[e][8], cells[e] (8 packed bytes), and per-parity-class records
// edata[class][e] = {wA, wB, cellA|cellB<<8, s} (used by the L0 build).
__global__ void edge_geom_kernel(const float* __restrict__ posq, const float* __restrict__ poss,
                                 const int* __restrict__ q_idx, const int* __restrict__ s_idx,
                                 int E, float* __restrict__ wgt, uint2* __restrict__ cells,
                                 uint4* __restrict__ edata) {
    int e = blockIdx.x * blockDim.x + threadIdx.x;
    if (e >= E) return;
    int q = q_idx[e], s = s_idx[e];
    float dx = (poss[s * 3 + 0] - posq[q * 3 + 0]) * INV_R;
    float dy = (poss[s * 3 + 1] - posq[q * 3 + 1]) * INV_R;
    float dz = (poss[s * 3 + 2] - posq[q * 3 + 2]) * INV_R;
    float r2 = dx * dx + dy * dy + dz * dz;
    float w1 = 1.f - r2;
    float win = fminf(fmaxf(w1 * w1 * w1, 0.f), 1.f);
    float bx, by, bz;
    ball_to_cube_dev(dx, dy, dz, bx, by, bz);
    float gx = (bx + 1.f) * 1.5f, gy = (by + 1.f) * 1.5f, gz = (bz + 1.f) * 1.5f;
    int ix = min(max((int)floorf(gx), 0), 2);
    int iy = min(max((int)floorf(gy), 0), 2);
    int iz = min(max((int)floorf(gz), 0), 2);
    float fx = gx - (float)ix, fy = gy - (float)iy, fz = gz - (float)iz;
    float wv[8];
    unsigned int cl[8];
#pragma unroll
    for (int c = 0; c < 8; c++) {
        int cbx = (c >> 2) & 1, cby = (c >> 1) & 1, cbz = c & 1;
        int jx = ix + cbx, jy = iy + cby, jz = iz + cbz;
        cl[c] = (unsigned int)((jx * 4 + jy) * 4 + jz);
        wv[c] = win * (cbx ? fx : 1.f - fx) * (cby ? fy : 1.f - fy) * (cbz ? fz : 1.f - fz);
    }
    float4* wp = (float4*)(wgt + (size_t)e * 8);
    wp[0] = make_float4(wv[0], wv[1], wv[2], wv[3]);
    wp[1] = make_float4(wv[4], wv[5], wv[6], wv[7]);
    uint2 cp;
    cp.x = cl[0] | (cl[1] << 8) | (cl[2] << 16) | (cl[3] << 24);
    cp.y = cl[4] | (cl[5] << 8) | (cl[6] << 16) | (cl[7] << 24);
    cells[e] = cp;
#pragma unroll
    for (int w = 0; w < 4; w++) {
        int pa = w >> 1, pb = w & 1;
        int cby = pa ^ (iy & 1), cbz = pb ^ (iz & 1);
        int cA = cby * 2 + cbz;
        uint4 d;
        d.x = __float_as_uint(wv[cA]);
        d.y = __float_as_uint(wv[cA + 4]);
        d.z = cl[cA] | (cl[cA + 4] << 8);
        d.w = (unsigned)s;
        edata[(size_t)w * E + e] = d;
    }
}

// a_df = fl @ w_d0 + b_d0 -> x96[:, 64:96]
__global__ void dense0_kernel(const float* __restrict__ fl, const float* __restrict__ w,
                              const float* __restrict__ b, int n, float* __restrict__ x96) {
    int i = blockIdx.x * blockDim.x + threadIdx.x;
    if (i >= n * 32) return;
    int q = i >> 5, o = i & 31;
    float acc = b[o];
#pragma unroll
    for (int c = 0; c < 4; c++) acc += fl[q * 4 + c] * w[c * 32 + o];
    x96[(size_t)q * 96 + 64 + o] = acc;
}

// C[q,o] = bias[o] (+resid[q,o]); zero if bias null (pre-init for atomic split-K).
__global__ void init_out_kernel(float* __restrict__ C, const float* __restrict__ bias,
                                const float* __restrict__ resid, int n, int co, int ldc) {
    int i = blockIdx.x * blockDim.x + threadIdx.x;
    if (i >= n * co) return;
    int q = i / co, o = i - q * co;
    float v = bias ? bias[o] : 0.f;
    if (resid) v += resid[(size_t)q * ldc + o];
    C[(size_t)q * ldc + o] = v;
}

// Wt[n][k] = bf16(W[k][n]) with W = [w_c (64*ci rows) ; w_d (ci rows)], K = 65*ci.
__global__ void wt_kernel(const float* __restrict__ wc, const float* __restrict__ wd,
                          int ci, int co, int K, unsigned short* __restrict__ Wt) {
    int i = blockIdx.x * blockDim.x + threadIdx.x;
    if (i >= co * K) return;
    int n = i / K, k = i - n * K;
    float v = (k < 64 * ci) ? wc[(size_t)k * co + n] : wd[(size_t)(k - 64 * ci) * co + n];
    Wt[i] = f2bf(v);
}

// Wt3[j=cell*3+o][k] = bf16(w_c3[cell][k][o]); 192 rows x 64 cols.
__global__ void wt3_kernel(const float* __restrict__ wc, unsigned short* __restrict__ Wt) {
    int i = blockIdx.x * blockDim.x + threadIdx.x;
    if (i >= 192 * 64) return;
    int j = i >> 6, k = i & 63;
    int cell = j / 3, o = j - cell * 3;
    Wt[i] = f2bf(wc[((size_t)cell * 64 + k) * 3 + o]);
}

// h = bf16(relu(x)), flat n elems.
__global__ void relu_bf16_kernel(const float* __restrict__ x, int n,
                                 unsigned short* __restrict__ h) {
    int i = blockIdx.x * blockDim.x + threadIdx.x;
    if (i < n) h[i] = f2bf(fmaxf(x[i], 0.f));
}

// Layer-0 G build, parity-partitioned (round-7 proven). 256 thr = 4 waves (classes);
// lane = edge-slot j(4) x corner k(2) x ch(8); replica per edge-slot. G out f32 [Q][64][CIN].
template <int CIN>
__global__ __launch_bounds__(256) void build_G0_par(
    const float* __restrict__ feat, const uint4* __restrict__ edata, int E,
    const int* __restrict__ row_ptr, int q0, float* __restrict__ G) {
    __shared__ float Gs[4 * 64 * 8];
    int lq = blockIdx.x, q = q0 + lq, t = threadIdx.x;
    int wave = t >> 6, lane = t & 63;
    int j = lane >> 4, k = (lane >> 3) & 1, ch = lane & 7;
    for (int i = t; i < 2048; i += 256) Gs[i] = 0.f;
    __syncthreads();
    int e0 = row_ptr[q], e1 = row_ptr[q + 1];
    int cnt = e1 - e0;
    if (cnt > 0) {
        int last = e1 - 1;
        const uint4* ed = edata + (size_t)wave * E;
        int nIt = (cnt + 3) >> 2;
        uint4 dA = ed[min(e0 + j, last)];
        uint4 dB = ed[min(e0 + 4 + j, last)];
        float fA = (ch < CIN) ? feat[(size_t)dA.w * CIN + ch] : 0.f;
        float* Gr = Gs + j * 512;
        for (int i = 0; i < nIt; i++) {
            uint4 dC = ed[min(e0 + (i + 2) * 4 + j, last)];
            float fB = (ch < CIN) ? feat[(size_t)dB.w * CIN + ch] : 0.f;
            bool v = (e0 + i * 4 + j) < e1;
            float w = v ? (k ? __uint_as_float(dA.y) : __uint_as_float(dA.x)) : 0.f;
            int cell = (int)((dA.z >> (k * 8)) & 255u);
            Gr[cell * 8 + ch] += w * fA;
            dA = dB; dB = dC; fA = fB;
        }
    }
    __syncthreads();
    size_t base = (size_t)lq * 64 * CIN;
    for (int i = t; i < 64 * CIN; i += 256) {
        int cell = i / CIN, c = i - cell * CIN;
        int o = cell * 8 + c;
        G[base + i] = Gs[o] + Gs[512 + o] + Gs[1024 + o] + Gs[1536 + o];
    }
}

// G build via per-query MFMA: G(64xCIN) = S^T(64xE) . F(ExCIN), chunks of 64 edges.
// S[cell][e] bf16 LDS (zeroed per chunk; every (cell,e) unique -> plain stores, no races).
// Ft[ch][e] bf16 LDS staged from pre-relu'd bf16 features hb. LDK=72 pad -> 2-way banks.
// A-frag = S rows (cells), B-frag = Ft rows (channels). Wave w owns cells [16w,16w+16).
// G out bf16 [Q][65][CIN]; slot 64 = hb[q].
template <int CIN>
__global__ __launch_bounds__(256) void build_G_mfma(
    const unsigned short* __restrict__ hb,
    const float* __restrict__ wgt, const uint2* __restrict__ cells,
    const int* __restrict__ s_idx, const int* __restrict__ row_ptr,
    int q0, unsigned short* __restrict__ G) {
    constexpr int LDK = 72;
    constexpr int CP = CIN / 2;
    constexpr int NT = CIN / 16;
    __shared__ unsigned short S[64 * LDK];
    __shared__ unsigned short Ft[CIN * LDK];
    int lq = blockIdx.x, q = q0 + lq, t = threadIdx.x;
    int wave = t >> 6, lane = t & 63;
    int e0 = row_ptr[q], e1 = row_ptr[q + 1];
    int nE = e1 - e0;
    float4v acc[NT];
#pragma unroll
    for (int i = 0; i < NT; i++) acc[i] = (float4v){0.f, 0.f, 0.f, 0.f};

    for (int c0 = 0; c0 < nE; c0 += 64) {
        int cnt = min(64, nE - c0);
        __syncthreads();  // prior chunk's MFMA reads done before overwrite
        for (int i = t; i < 64 * LDK / 2; i += 256) ((unsigned int*)S)[i] = 0u;
        for (int i = t; i < 64 * CP; i += 256) {
            int e = i / CP, cp = i - e * CP;
            unsigned v = 0u;
            if (e < cnt) {
                int s = s_idx[e0 + c0 + e];
                v = ((const unsigned int*)hb)[(size_t)s * CP + cp];
            }
            Ft[(2 * cp) * LDK + e] = (unsigned short)(v & 0xffffu);
            Ft[(2 * cp + 1) * LDK + e] = (unsigned short)(v >> 16);
        }
        {
            int e = t >> 2, cpair = t & 3;
            if (e < cnt) {
                int ee = e0 + c0 + e;
                uint2 cp = cells[ee];
                float w0 = wgt[(size_t)ee * 8 + cpair * 2];
                float w1 = wgt[(size_t)ee * 8 + cpair * 2 + 1];
                unsigned word = (cpair < 2) ? cp.x : cp.y;
                int sh = (cpair & 1) * 16;
                int cell0 = (int)((word >> sh) & 255u);
                int cell1 = (int)((word >> (sh + 8)) & 255u);
                S[cell0 * LDK + e] = f2bf(w0);
                S[cell1 * LDK + e] = f2bf(w1);
            }
        }
        __syncthreads();
        int kq = lane >> 4, mrow = lane & 15;
#pragma unroll
        for (int ks = 0; ks < 2; ks++) {
            int kk = ks * 32 + kq * 8;
            short8 a = *(const short8*)(S + (wave * 16 + mrow) * LDK + kk);
#pragma unroll
            for (int nt = 0; nt < NT; nt++) {
                short8 b = *(const short8*)(Ft + (nt * 16 + mrow) * LDK + kk);
                acc[nt] = __builtin_amdgcn_mfma_f32_16x16x32_bf16(a, b, acc[nt], 0, 0, 0);
            }
        }
    }
    unsigned short* Go = G + (size_t)lq * (size_t)(65 * CIN);
    int col = lane & 15, rq = lane >> 4;
#pragma unroll
    for (int nt = 0; nt < NT; nt++) {
#pragma unroll
        for (int r = 0; r < 4; r++) {
            int cell = wave * 16 + rq * 4 + r;
            Go[cell * CIN + nt * 16 + col] = f2bf(acc[nt][r]);
        }
    }
    if (t < CP) {
        ((unsigned int*)(Go + 64 * CIN))[t] = ((const unsigned int*)hb)[(size_t)q * CP + t];
    }
}

// bf16 MFMA GEMM, split-K atomics. A: [M][K] bf16 row-major; Wt: [64][K] bf16 (n-major).
__global__ __launch_bounds__(256) void gemm_mfma(
    const unsigned short* __restrict__ A, const unsigned short* __restrict__ Wt,
    float* __restrict__ C, int M, int K, int ldc, int kpb) {
    int wave = threadIdx.x >> 6, lane = threadIdx.x & 63;
    int m0 = blockIdx.x * 64;
    int kbeg = blockIdx.y * kpb;
    int kend = min(K, kbeg + kpb);
    int mrow = lane & 15, kq = lane >> 4;
    int n0 = wave * 16;
    const unsigned short* Bp = Wt + (size_t)(n0 + mrow) * K;
    float4v acc[4] = {{0.f, 0.f, 0.f, 0.f}, {0.f, 0.f, 0.f, 0.f},
                      {0.f, 0.f, 0.f, 0.f}, {0.f, 0.f, 0.f, 0.f}};
    int r0 = min(m0 + mrow, M - 1);
    int r1 = min(m0 + 16 + mrow, M - 1);
    int r2 = min(m0 + 32 + mrow, M - 1);
    int r3 = min(m0 + 48 + mrow, M - 1);
    const unsigned short* A0 = A + (size_t)r0 * K;
    const unsigned short* A1 = A + (size_t)r1 * K;
    const unsigned short* A2 = A + (size_t)r2 * K;
    const unsigned short* A3 = A + (size_t)r3 * K;
    for (int k0 = kbeg; k0 < kend; k0 += 32) {
        int kk = k0 + kq * 8;
        short8 b = *(const short8*)(Bp + kk);
        short8 a0 = *(const short8*)(A0 + kk);
        short8 a1 = *(const short8*)(A1 + kk);
        short8 a2 = *(const short8*)(A2 + kk);
        short8 a3 = *(const short8*)(A3 + kk);
        acc[0] = __builtin_amdgcn_mfma_f32_16x16x32_bf16(a0, b, acc[0], 0, 0, 0);
        acc[1] = __builtin_amdgcn_mfma_f32_16x16x32_bf16(a1, b, acc[1], 0, 0, 0);
        acc[2] = __builtin_amdgcn_mfma_f32_16x16x32_bf16(a2, b, acc[2], 0, 0, 0);
        acc[3] = __builtin_amdgcn_mfma_f32_16x16x32_bf16(a3, b, acc[3], 0, 0, 0);
    }
    int col = lane & 15, rq = lane >> 4;
#pragma unroll
    for (int mt = 0; mt < 4; mt++) {
#pragma unroll
        for (int r = 0; r < 4; r++) {
            int m = m0 + mt * 16 + rq * 4 + r;
            if (m < M) atomicAdd(&C[(size_t)m * ldc + n0 + col], acc[mt][r]);
        }
    }
}

// bf16 MFMA GEMM, f32 direct store, N-tiled via blockIdx.y, full K (layer-3 P).
__global__ __launch_bounds__(256) void gemm_mfma_store(
    const unsigned short* __restrict__ A, const unsigned short* __restrict__ Wt,
    float* __restrict__ C, int M, int K, int ldc) {
    int wave = threadIdx.x >> 6, lane = threadIdx.x & 63;
    int m0 = blockIdx.x * 64;
    int n0 = blockIdx.y * 64 + wave * 16;
    int mrow = lane & 15, kq = lane >> 4;
    const unsigned short* Bp = Wt + (size_t)(n0 + mrow) * K;
    float4v acc[4] = {{0.f, 0.f, 0.f, 0.f}, {0.f, 0.f, 0.f, 0.f},
                      {0.f, 0.f, 0.f, 0.f}, {0.f, 0.f, 0.f, 0.f}};
    int r0 = min(m0 + mrow, M - 1);
    int r1 = min(m0 + 16 + mrow, M - 1);
    int r2 = min(m0 + 32 + mrow, M - 1);
    int r3 = min(m0 + 48 + mrow, M - 1);
    const unsigned short* A0 = A + (size_t)r0 * K;
    const unsigned short* A1 = A + (size_t)r1 * K;
    const unsigned short* A2 = A + (size_t)r2 * K;
    const unsigned short* A3 = A + (size_t)r3 * K;
    for (int k0 = 0; k0 < K; k0 += 32) {
        int kk = k0 + kq * 8;
        short8 b = *(const short8*)(Bp + kk);
        short8 a0 = *(const short8*)(A0 + kk);
        short8 a1 = *(const short8*)(A1 + kk);
        short8 a2 = *(const short8*)(A2 + kk);
        short8 a3 = *(const short8*)(A3 + kk);
        acc[0] = __builtin_amdgcn_mfma_f32_16x16x32_bf16(a0, b, acc[0], 0, 0, 0);
        acc[1] = __builtin_amdgcn_mfma_f32_16x16x32_bf16(a1, b, acc[1], 0, 0, 0);
        acc[2] = __builtin_amdgcn_mfma_f32_16x16x32_bf16(a2, b, acc[2], 0, 0, 0);
        acc[3] = __builtin_amdgcn_mfma_f32_16x16x32_bf16(a3, b, acc[3], 0, 0, 0);
    }
    int col = lane & 15, rq = lane >> 4;
#pragma unroll
    for (int mt = 0; mt < 4; mt++) {
#pragma unroll
        for (int r = 0; r < 4; r++) {
            int m = m0 + mt * 16 + rq * 4 + r;
            if (m < M) C[(size_t)m * ldc + n0 + col] = acc[mt][r];
        }
    }
}

// Layer 3: y3[q] = sum_edges sum_corners w * P[s][cell*3+o] + relu(x64b[q])@w_d3 + b_d3.
__global__ __launch_bounds__(256) void conv3_reduce(
    const float* __restrict__ P,
    const float* __restrict__ wgt, const uint2* __restrict__ cells,
    const int* __restrict__ s_idx, const int* __restrict__ row_ptr,
    const unsigned short* __restrict__ hq, const float* __restrict__ wd3,
    const float* __restrict__ b3, int n, float* __restrict__ y3) {
    int wave = threadIdx.x >> 6, lane = threadIdx.x & 63;
    int q = blockIdx.x * 4 + wave;
    if (q >= n) return;
    float a0 = 0.f, a1 = 0.f, a2 = 0.f;
    int e0 = row_ptr[q], e1 = row_ptr[q + 1];
    for (int e = e0 + lane; e < e1; e += 64) {
        int s = s_idx[e];
        uint2 cp = cells[e];
        const float4* wp = (const float4*)(wgt + (size_t)e * 8);
        float4 wa = wp[0], wb = wp[1];
        const float* Ps = P + (size_t)s * 192;
        float wv[8] = {wa.x, wa.y, wa.z, wa.w, wb.x, wb.y, wb.z, wb.w};
#pragma unroll
        for (int c = 0; c < 8; c++) {
            unsigned word = (c < 4) ? cp.x : cp.y;
            int cell = (int)((word >> ((c & 3) * 8)) & 255u);
            const float* pc = Ps + cell * 3;
            a0 += wv[c] * pc[0];
            a1 += wv[c] * pc[1];
            a2 += wv[c] * pc[2];
        }
    }
    float hv = bf2f(hq[(size_t)q * 64 + lane]);
    a0 += hv * wd3[lane * 3 + 0];
    a1 += hv * wd3[lane * 3 + 1];
    a2 += hv * wd3[lane * 3 + 2];
#pragma unroll
    for (int off = 32; off > 0; off >>= 1) {
        a0 += __shfl_xor(a0, off);
        a1 += __shfl_xor(a1, off);
        a2 += __shfl_xor(a2, off);
    }
    if (lane == 0) {
        y3[(size_t)q * 3 + 0] = a0 + b3[0];
        y3[(size_t)q * 3 + 1] = a1 + b3[1];
        y3[(size_t)q * 3 + 2] = a2 + b3[2];
    }
}

// f32 split-K GEMM (layer 0 only, tiny K).
template <int BM, int BN, int BK, int TM, int TN>
__global__ void gemm_atomic(const float* __restrict__ A, const float* __restrict__ B,
                            float* __restrict__ C, int M, int N, int K,
                            int ldc, int coff, int kpb) {
    constexpr int THREADS = (BM / TM) * (BN / TN);
    __shared__ float As[BK][BM + 1];
    __shared__ float Bs[BK][BN + 1];
    int tx = threadIdx.x;
    int tcols = BN / TN;
    int tcol = tx % tcols, trow = tx / tcols;
    int m0 = blockIdx.x * BM;
    int kbeg = blockIdx.y * kpb;
    int kend = min(K, kbeg + kpb);
    float acc[TM][TN];
#pragma unroll
    for (int i = 0; i < TM; i++)
#pragma unroll
        for (int j = 0; j < TN; j++) acc[i][j] = 0.f;
    for (int k0 = kbeg; k0 < kend; k0 += BK) {
        for (int i = tx; i < BM * BK; i += THREADS) {
            int kk = i % BK, mm = i / BK;
            int m = m0 + mm, k = k0 + kk;
            As[kk][mm] = (m < M && k < K) ? A[(size_t)m * K + k] : 0.f;
        }
        for (int i = tx; i < BN * BK; i += THREADS) {
            int nn = i % BN, kk = i / BN;
            int k = k0 + kk;
            Bs[kk][nn] = (k < K && nn < N) ? B[(size_t)k * N + nn] : 0.f;
        }
        __syncthreads();
#pragma unroll
        for (int kk = 0; kk < BK; kk++) {
            float a[TM], b[TN];
#pragma unroll
            for (int i = 0; i < TM; i++) a[i] = As[kk][trow * TM + i];
#pragma unroll
            for (int j = 0; j < TN; j++) b[j] = Bs[kk][tcol * TN + j];
#pragma unroll
            for (int i = 0; i < TM; i++)
#pragma unroll
                for (int j = 0; j < TN; j++) acc[i][j] += a[i] * b[j];
        }
        __syncthreads();
    }
    for (int i = 0; i < TM; i++) {
        int m = m0 + trow * TM + i;
        if (m >= M) continue;
        for (int j = 0; j < TN; j++) {
            int nn = tcol * TN + j;
            if (nn >= N) continue;
            atomicAdd(&C[(size_t)m * ldc + coff + nn], acc[i][j]);
        }
    }
}

__global__ void final_kernel(const float* __restrict__ pos, const float* __restrict__ pos2,
                             const float* __restrict__ y3, int n, float* __restrict__ out) {
    int i = blockIdx.x * blockDim.x + threadIdx.x;
    if (i >= n * 3) return;
    float pn = pos2[i] + y3[i] * (1.f / 128.f);
    out[i] = pn;
    out[n * 3 + i] = (pn - pos[i]) * (1.f / DT_F);
}

extern "C" void kernel_launch(void* const* d_in, const int* in_sizes, int n_in,
                              void* d_out, int out_size, void* d_ws, size_t ws_size,
                              hipStream_t stream) {
    const float* pos       = (const float*)d_in[0];
    const float* vel       = (const float*)d_in[1];
    const float* box       = (const float*)d_in[2];
    const float* box_feats = (const float*)d_in[3];
    const int*   ff_q      = (const int*)d_in[4];
    const int*   ff_s      = (const int*)d_in[5];
    const int*   fo_q      = (const int*)d_in[6];
    const int*   fo_s      = (const int*)d_in[7];
    const float* w_cf0     = (const float*)d_in[8];
    const float* w_co0     = (const float*)d_in[9];
    const float* w_d0      = (const float*)d_in[10];
    const float* b_d0      = (const float*)d_in[11];
    const float* w_c1      = (const float*)d_in[12];
    const float* w_d1      = (const float*)d_in[13];
    const float* b_d1      = (const float*)d_in[14];
    const float* w_c2      = (const float*)d_in[15];
    const float* w_d2      = (const float*)d_in[16];
    const float* b_d2      = (const float*)d_in[17];
    const float* w_c3      = (const float*)d_in[18];
    const float* w_d3      = (const float*)d_in[19];
    const float* b_d3      = (const float*)d_in[20];
    float* out = (float*)d_out;

    int n   = in_sizes[0] / 3;
    int Eff = in_sizes[4];
    int Efo = in_sizes[6];

    float* base = (float*)d_ws;
    size_t off = 0;
    auto alloc = [&](size_t nf) { float* p = base + off; off += (nf + 3) & ~(size_t)3; return p; };
    float* pos2  = alloc((size_t)n * 3);
    float* fl    = alloc((size_t)n * 4);
    float* x96   = alloc((size_t)n * 96);
    float* x64a  = alloc((size_t)n * 64);
    float* x64b  = alloc((size_t)n * 64);
    float* y3    = alloc((size_t)n * 3);
    int* rp_ff   = (int*)alloc((size_t)n + 1);
    int* rp_fo   = (int*)alloc((size_t)n + 1);
    unsigned short* Wt   = (unsigned short*)alloc((size_t)65 * 96 * 64 / 2);
    unsigned short* Wt3  = (unsigned short*)alloc((size_t)192 * 64 / 2);
    unsigned short* hb96 = (unsigned short*)alloc((size_t)n * 48);   // [n][96] bf16
    unsigned short* hb64 = (unsigned short*)alloc((size_t)n * 32);   // [n][64] bf16
    float* P3    = alloc((size_t)n * 192);
    float* wgt_ff = alloc((size_t)Eff * 8);
    uint2* cl_ff  = (uint2*)alloc((size_t)Eff * 2);
    float* wgt_fo = alloc((size_t)Efo * 8);
    uint2* cl_fo  = (uint2*)alloc((size_t)Efo * 2);
    uint4* ed_ff  = (uint4*)alloc((size_t)Eff * 16);
    uint4* ed_fo  = (uint4*)alloc((size_t)Efo * 16);
    float* G = base + off;                                  // f32 view (layer 0)
    unsigned short* Gb = (unsigned short*)G;                // bf16 view (layers 1-2)

    size_t totalF = ws_size / sizeof(float);
    size_t availF = (totalF > off) ? (totalF - off) : 0;
    auto chunkQ = [&](size_t floatsPerQ, int cap) {
        long q = (long)(availF / floatsPerQ);
        if (q < 1) q = 1;
        if (q > n) q = n;
        if (q > cap) q = cap;
        return (int)q;
    };

    // --- prep, CSR, edge geometry (once) ---
    prep_kernel<<<cdiv(n, 256), 256, 0, stream>>>(pos, vel, n, pos2, fl);
    row_ptr_kernel<<<cdiv(n + 1, 256), 256, 0, stream>>>(ff_q, Eff, n, rp_ff);
    row_ptr_kernel<<<cdiv(n + 1, 256), 256, 0, stream>>>(fo_q, Efo, n, rp_fo);
    edge_geom_kernel<<<cdiv(Eff, 256), 256, 0, stream>>>(pos2, pos2, ff_q, ff_s, Eff, wgt_ff, cl_ff, ed_ff);
    edge_geom_kernel<<<cdiv(Efo, 256), 256, 0, stream>>>(pos2, box, fo_q, fo_s, Efo, wgt_fo, cl_fo, ed_fo);

    // --- layer 0 (f32 path, tiny K) ---
    init_out_kernel<<<cdiv(n * 64, 256), 256, 0, stream>>>(x96, nullptr, nullptr, n, 64, 96);
    dense0_kernel<<<cdiv(n * 32, 256), 256, 0, stream>>>(fl, w_d0, b_d0, n, x96);
    {
        int Q = chunkQ(64 * 4, n);
        for (int q0 = 0; q0 < n; q0 += Q) {
            int mc = std::min(Q, n - q0);
            build_G0_par<4><<<mc, 256, 0, stream>>>(fl, ed_ff, Eff, rp_ff, q0, G);
            gemm_atomic<64, 32, 16, 4, 2><<<dim3(cdiv(mc, 64), 4), 256, 0, stream>>>(
                G, w_cf0, x96 + (size_t)q0 * 96, mc, 32, 256, 96, 32, 4 * 16);
        }
    }
    {
        int Q = chunkQ(64 * 3, n);
        for (int q0 = 0; q0 < n; q0 += Q) {
            int mc = std::min(Q, n - q0);
            build_G0_par<3><<<mc, 256, 0, stream>>>(box_feats, ed_fo, Efo, rp_fo, q0, G);
            gemm_atomic<64, 32, 16, 4, 2><<<dim3(cdiv(mc, 64), 4), 256, 0, stream>>>(
                G, w_co0, x96 + (size_t)q0 * 96, mc, 32, 192, 96, 0, 3 * 16);
        }
    }

    // --- layer 1: 96 -> 64, MFMA build + MFMA gemm (chunked for L3 residency) ---
    {
        const int K = 65 * 96;
        wt_kernel<<<cdiv(64 * K, 256), 256, 0, stream>>>(w_c1, w_d1, 96, 64, K, Wt);
        init_out_kernel<<<cdiv(n * 64, 256), 256, 0, stream>>>(x64a, b_d1, nullptr, n, 64, 64);
        relu_bf16_kernel<<<cdiv(n * 96, 256), 256, 0, stream>>>(x96, n * 96, hb96);
        int Q = chunkQ((size_t)K / 2, 8192);
        for (int q0 = 0; q0 < n; q0 += Q) {
            int mc = std::min(Q, n - q0);
            build_G_mfma<96><<<mc, 256, 0, stream>>>(
                hb96, wgt_ff, cl_ff, ff_s, rp_ff, q0, Gb);
            gemm_mfma<<<dim3(cdiv(mc, 64), 8), 256, 0, stream>>>(
                Gb, Wt, x64a + (size_t)q0 * 64, mc, K, 64, cdiv(K / 32, 8) * 32);
        }
    }

    // --- layer 2: 64 -> 64, residual, MFMA build + MFMA gemm (chunked) ---
    {
        const int K = 65 * 64;
        wt_kernel<<<cdiv(64 * K, 256), 256, 0, stream>>>(w_c2, w_d2, 64, 64, K, Wt);
        init_out_kernel<<<cdiv(n * 64, 256), 256, 0, stream>>>(x64b, b_d2, x64a, n, 64, 64);
        relu_bf16_kernel<<<cdiv(n * 64, 256), 256, 0, stream>>>(x64a, n * 64, hb64);
        int Q = chunkQ((size_t)K / 2, 8192);
        for (int q0 = 0; q0 < n; q0 += Q) {
            int mc = std::min(Q, n - q0);
            build_G_mfma<64><<<mc, 256, 0, stream>>>(
                hb64, wgt_ff, cl_ff, ff_s, rp_ff, q0, Gb);
            gemm_mfma<<<dim3(cdiv(mc, 64), 8), 256, 0, stream>>>(
                Gb, Wt, x64b + (size_t)q0 * 64, mc, K, 64, cdiv(K / 32, 8) * 32);
        }
    }

    // --- layer 3: 64 -> 3 via P-trick (3-channel P stays cache-resident) ---
    {
        relu_bf16_kernel<<<cdiv(n * 64, 256), 256, 0, stream>>>(x64b, n * 64, hb64);
        wt3_kernel<<<cdiv(192 * 64, 256), 256, 0, stream>>>(w_c3, Wt3);
        gemm_mfma_store<<<dim3(cdiv(n, 64), 3), 256, 0, stream>>>(hb64, Wt3, P3, n, 64, 192);
        conv3_reduce<<<cdiv(n, 4), 256, 0, stream>>>(
            P3, wgt_ff, cl_ff, ff_s, rp_ff, hb64, w_d3, b_d3, n, y3);
    }

    final_kernel<<<cdiv(n * 3, 256), 256, 0, stream>>>(pos, pos2, y3, n, out);
}

// Round 12
// 828.611 us; speedup vs baseline: 1.0971x; 1.0971x over previous
//
#include <hip/hip_runtime.h>
#include <algorithm>

#define DT_F 0.02f
#define INV_R (1.0f / 0.1125f)

typedef __attribute__((ext_vector_type(8))) short short8;
typedef __attribute__((ext_vector_type(4))) float float4v;

static inline int cdiv(int a, int b) { return (a + b - 1) / b; }

__device__ __forceinline__ float sgnf(float v) {
    return (v > 0.f) ? 1.f : ((v < 0.f) ? -1.f : 0.f);
}

__device__ __forceinline__ unsigned short f2bf(float f) {
    union { float f; unsigned u; } v; v.f = f;
    return (unsigned short)((v.u + 0x7fffu + ((v.u >> 16) & 1u)) >> 16);
}
__device__ __forceinline__ float bf2f(unsigned short h) {
    union { unsigned u; float f; } v; v.u = ((unsigned)h) << 16;
    return v.f;
}

// Exact port of reference ball_to_cube (f32).
__device__ __forceinline__ void ball_to_cube_dev(float x, float y, float z,
                                                 float& ox, float& oy, float& oz) {
    const float eps = 1e-12f;
    float sq = x * x + y * y + z * z;
    float nrm = sqrtf(sq + eps);
    float xy2 = x * x + y * y;
    bool cap = 1.25f * z * z > xy2;
    float s_cap = sqrtf(3.f * nrm / (nrm + fabsf(z) + eps));
    float s_side = nrm / sqrtf(xy2 + eps);
    float s = cap ? s_cap : s_side;
    float xc = x * s, yc = y * s;
    float zc = cap ? sgnf(z) * nrm : 1.5f * z;
    if (!(sq > eps)) { xc = 0.f; yc = 0.f; zc = 0.f; }
    float rxy = sqrtf(xc * xc + yc * yc + eps);
    bool xbig = fabsf(yc) <= fabsf(xc);
    float dx = (fabsf(xc) > eps) ? xc : 1.f;
    float dy = (fabsf(yc) > eps) ? yc : 1.f;
    const float c4pi = 1.27323954473516276f;  // 4/pi
    float tx = sgnf(xc) * rxy, ty = sgnf(yc) * rxy;
    float xq = xbig ? tx : ty * c4pi * atanf(xc / dy);
    float yq = xbig ? tx * c4pi * atanf(yc / dx) : ty;
    if (!(xc * xc + yc * yc > eps)) { xq = 0.f; yq = 0.f; }
    ox = xq; oy = yq; oz = zc;
}

__global__ void prep_kernel(const float* __restrict__ pos, const float* __restrict__ vel,
                            int n, float* __restrict__ pos2, float* __restrict__ fl) {
    int i = blockIdx.x * blockDim.x + threadIdx.x;
    if (i >= n) return;
    float v0 = vel[i * 3 + 0], v1 = vel[i * 3 + 1], v2 = vel[i * 3 + 2];
    float u0 = v0, u1 = v1 + DT_F * (-9.81f), u2 = v2;
    pos2[i * 3 + 0] = pos[i * 3 + 0] + DT_F * (u0 + v0) * 0.5f;
    pos2[i * 3 + 1] = pos[i * 3 + 1] + DT_F * (u1 + v1) * 0.5f;
    pos2[i * 3 + 2] = pos[i * 3 + 2] + DT_F * (u2 + v2) * 0.5f;
    fl[i * 4 + 0] = 1.f;
    fl[i * 4 + 1] = u0;
    fl[i * 4 + 2] = u1;
    fl[i * 4 + 3] = u2;
}

__global__ void row_ptr_kernel(const int* __restrict__ q_idx, int E, int nq,
                               int* __restrict__ row_ptr) {
    int q = blockIdx.x * blockDim.x + threadIdx.x;
    if (q > nq) return;
    int lo = 0, hi = E;
    while (lo < hi) {
        int mid = (lo + hi) >> 1;
        if (q_idx[mid] < q) lo = mid + 1; else hi = mid;
    }
    row_ptr[q] = lo;
}

// Per-edge geometry once; ix clamped to [0,2] => 8 distinct corners.
// Outputs: wgt[e][8] (win folded), cells[e] = 8 packed cell bytes.
__global__ void edge_geom_kernel(const float* __restrict__ posq, const float* __restrict__ poss,
                                 const int* __restrict__ q_idx, const int* __restrict__ s_idx,
                                 int E, float* __restrict__ wgt, uint2* __restrict__ cells) {
    int e = blockIdx.x * blockDim.x + threadIdx.x;
    if (e >= E) return;
    int q = q_idx[e], s = s_idx[e];
    float dx = (poss[s * 3 + 0] - posq[q * 3 + 0]) * INV_R;
    float dy = (poss[s * 3 + 1] - posq[q * 3 + 1]) * INV_R;
    float dz = (poss[s * 3 + 2] - posq[q * 3 + 2]) * INV_R;
    float r2 = dx * dx + dy * dy + dz * dz;
    float w1 = 1.f - r2;
    float win = fminf(fmaxf(w1 * w1 * w1, 0.f), 1.f);
    float bx, by, bz;
    ball_to_cube_dev(dx, dy, dz, bx, by, bz);
    float gx = (bx + 1.f) * 1.5f, gy = (by + 1.f) * 1.5f, gz = (bz + 1.f) * 1.5f;
    int ix = min(max((int)floorf(gx), 0), 2);
    int iy = min(max((int)floorf(gy), 0), 2);
    int iz = min(max((int)floorf(gz), 0), 2);
    float fx = gx - (float)ix, fy = gy - (float)iy, fz = gz - (float)iz;
    float wv[8];
    unsigned int cl[8];
#pragma unroll
    for (int c = 0; c < 8; c++) {
        int cbx = (c >> 2) & 1, cby = (c >> 1) & 1, cbz = c & 1;
        int jx = ix + cbx, jy = iy + cby, jz = iz + cbz;
        cl[c] = (unsigned int)((jx * 4 + jy) * 4 + jz);
        wv[c] = win * (cbx ? fx : 1.f - fx) * (cby ? fy : 1.f - fy) * (cbz ? fz : 1.f - fz);
    }
    float4* wp = (float4*)(wgt + (size_t)e * 8);
    wp[0] = make_float4(wv[0], wv[1], wv[2], wv[3]);
    wp[1] = make_float4(wv[4], wv[5], wv[6], wv[7]);
    uint2 cp;
    cp.x = cl[0] | (cl[1] << 8) | (cl[2] << 16) | (cl[3] << 24);
    cp.y = cl[4] | (cl[5] << 8) | (cl[6] << 16) | (cl[7] << 24);
    cells[e] = cp;
}

// x96 init: cols 0:64 = 0 (conv targets), cols 64:96 = b_d0 (dense bias).
__global__ void init_x96_kernel(float* __restrict__ x96, const float* __restrict__ b0, int n) {
    int i = blockIdx.x * blockDim.x + threadIdx.x;
    if (i >= n * 96) return;
    int o = i % 96;
    x96[i] = (o >= 64) ? b0[o - 64] : 0.f;
}

// C[q,o] = bias[o] (+resid[q,o]) (pre-init for atomic split-K).
__global__ void init_out_kernel(float* __restrict__ C, const float* __restrict__ bias,
                                const float* __restrict__ resid, int n, int co, int ldc) {
    int i = blockIdx.x * blockDim.x + threadIdx.x;
    if (i >= n * co) return;
    int q = i / co, o = i - q * co;
    float v = bias ? bias[o] : 0.f;
    if (resid) v += resid[(size_t)q * ldc + o];
    C[(size_t)q * ldc + o] = v;
}

// Wt[n][k] = bf16(W[k][n]) with W = [w_c (64*ci rows) ; w_d (ci rows)], K = 65*ci.
__global__ void wt_kernel(const float* __restrict__ wc, const float* __restrict__ wd,
                          int ci, int co, int K, unsigned short* __restrict__ Wt) {
    int i = blockIdx.x * blockDim.x + threadIdx.x;
    if (i >= co * K) return;
    int n = i / K, k = i - n * K;
    float v = (k < 64 * ci) ? wc[(size_t)k * co + n] : wd[(size_t)(k - 64 * ci) * co + n];
    Wt[i] = f2bf(v);
}

// L0 fluid Wt: [64][1056]; slot=k>>4, c=k&15. Out cols 0:32 = conv w_cf0 (CI=4, CO=32),
// cols 32:64 = dense w_d0 (slot 64). Slots padded with zeros (c>=CI, slot 65).
__global__ void wt0f_kernel(const float* __restrict__ wcf, const float* __restrict__ wd,
                            unsigned short* __restrict__ Wt) {
    int i = blockIdx.x * blockDim.x + threadIdx.x;
    if (i >= 64 * 1056) return;
    int nrow = i / 1056, k = i - nrow * 1056;
    int slot = k >> 4, c = k & 15;
    float v = 0.f;
    if (nrow < 32) {
        if (slot < 64 && c < 4) v = wcf[((size_t)slot * 4 + c) * 32 + nrow];
    } else {
        if (slot == 64 && c < 4) v = wd[c * 32 + (nrow - 32)];
    }
    Wt[i] = f2bf(v);
}

// L0 box Wt: [64][1056]; out cols 0:32 = conv w_co0 (CI=3); cols 32:64 = 0.
__global__ void wt0b_kernel(const float* __restrict__ wco, unsigned short* __restrict__ Wt) {
    int i = blockIdx.x * blockDim.x + threadIdx.x;
    if (i >= 64 * 1056) return;
    int nrow = i / 1056, k = i - nrow * 1056;
    int slot = k >> 4, c = k & 15;
    float v = 0.f;
    if (nrow < 32 && slot < 64 && c < 3) v = wco[((size_t)slot * 3 + c) * 32 + nrow];
    Wt[i] = f2bf(v);
}

// Wt3[j=cell*3+o][k] = bf16(w_c3[cell][k][o]); 192 rows x 64 cols.
__global__ void wt3_kernel(const float* __restrict__ wc, unsigned short* __restrict__ Wt) {
    int i = blockIdx.x * blockDim.x + threadIdx.x;
    if (i >= 192 * 64) return;
    int j = i >> 6, k = i & 63;
    int cell = j / 3, o = j - cell * 3;
    Wt[i] = f2bf(wc[((size_t)cell * 64 + k) * 3 + o]);
}

// h = bf16(relu(x)), flat n elems.
__global__ void relu_bf16_kernel(const float* __restrict__ x, int n,
                                 unsigned short* __restrict__ h) {
    int i = blockIdx.x * blockDim.x + threadIdx.x;
    if (i < n) h[i] = f2bf(fmaxf(x[i], 0.f));
}

// dst[q][0..15] = bf16(src[q][0..c-1]) zero-padded to 16.
__global__ void pad16_bf16(const float* __restrict__ src, int n, int c,
                           unsigned short* __restrict__ dst) {
    int i = blockIdx.x * blockDim.x + threadIdx.x;
    if (i >= n * 16) return;
    int q = i >> 4, k = i & 15;
    dst[i] = (k < c) ? f2bf(src[q * c + k]) : (unsigned short)0;
}

// G build via per-query MFMA: G(64xCIN) = S^T(64xE) . F(ExCIN), chunks of 64 edges.
// S[cell][e] bf16 LDS (zeroed per chunk; every (cell,e) unique -> plain stores, no races).
// Ft[ch][e] bf16 LDS staged from bf16 features hb (row stride CIN). LDK=72 pad.
// Wave w owns cells [16w,16w+16). G out bf16 [Q][SLOTS][CIN]; slot 64 = hb[q],
// slots >= 65 zero (K padding so 16*SLOTS is a multiple of 32).
template <int CIN, int SLOTS>
__global__ __launch_bounds__(256) void build_G_mfma(
    const unsigned short* __restrict__ hb,
    const float* __restrict__ wgt, const uint2* __restrict__ cells,
    const int* __restrict__ s_idx, const int* __restrict__ row_ptr,
    int q0, unsigned short* __restrict__ G) {
    constexpr int LDK = 72;
    constexpr int CP = CIN / 2;
    constexpr int NT = CIN / 16;
    __shared__ unsigned short S[64 * LDK];
    __shared__ unsigned short Ft[CIN * LDK];
    int lq = blockIdx.x, q = q0 + lq, t = threadIdx.x;
    int wave = t >> 6, lane = t & 63;
    int e0 = row_ptr[q], e1 = row_ptr[q + 1];
    int nE = e1 - e0;
    float4v acc[NT];
#pragma unroll
    for (int i = 0; i < NT; i++) acc[i] = (float4v){0.f, 0.f, 0.f, 0.f};

    for (int c0 = 0; c0 < nE; c0 += 64) {
        int cnt = min(64, nE - c0);
        __syncthreads();  // prior chunk's MFMA reads done before overwrite
        for (int i = t; i < 64 * LDK / 2; i += 256) ((unsigned int*)S)[i] = 0u;
        for (int i = t; i < 64 * CP; i += 256) {
            int e = i / CP, cp = i - e * CP;
            unsigned v = 0u;
            if (e < cnt) {
                int s = s_idx[e0 + c0 + e];
                v = ((const unsigned int*)hb)[(size_t)s * CP + cp];
            }
            Ft[(2 * cp) * LDK + e] = (unsigned short)(v & 0xffffu);
            Ft[(2 * cp + 1) * LDK + e] = (unsigned short)(v >> 16);
        }
        {
            int e = t >> 2, cpair = t & 3;
            if (e < cnt) {
                int ee = e0 + c0 + e;
                uint2 cp = cells[ee];
                float w0 = wgt[(size_t)ee * 8 + cpair * 2];
                float w1 = wgt[(size_t)ee * 8 + cpair * 2 + 1];
                unsigned word = (cpair < 2) ? cp.x : cp.y;
                int sh = (cpair & 1) * 16;
                int cell0 = (int)((word >> sh) & 255u);
                int cell1 = (int)((word >> (sh + 8)) & 255u);
                S[cell0 * LDK + e] = f2bf(w0);
                S[cell1 * LDK + e] = f2bf(w1);
            }
        }
        __syncthreads();
        int kq = lane >> 4, mrow = lane & 15;
#pragma unroll
        for (int ks = 0; ks < 2; ks++) {
            int kk = ks * 32 + kq * 8;
            short8 a = *(const short8*)(S + (wave * 16 + mrow) * LDK + kk);
#pragma unroll
            for (int nt = 0; nt < NT; nt++) {
                short8 b = *(const short8*)(Ft + (nt * 16 + mrow) * LDK + kk);
                acc[nt] = __builtin_amdgcn_mfma_f32_16x16x32_bf16(a, b, acc[nt], 0, 0, 0);
            }
        }
    }
    unsigned short* Go = G + (size_t)lq * (size_t)(SLOTS * CIN);
    int col = lane & 15, rq = lane >> 4;
#pragma unroll
    for (int nt = 0; nt < NT; nt++) {
#pragma unroll
        for (int r = 0; r < 4; r++) {
            int cell = wave * 16 + rq * 4 + r;
            Go[cell * CIN + nt * 16 + col] = f2bf(acc[nt][r]);
        }
    }
    if (t < CP) {
        ((unsigned int*)(Go + 64 * CIN))[t] = ((const unsigned int*)hb)[(size_t)q * CP + t];
    }
    if (SLOTS > 65) {
        if (t < (SLOTS - 65) * CP) ((unsigned int*)(Go + 65 * CIN))[t] = 0u;
    }
}

// bf16 MFMA GEMM, split-K atomics. A: [M][K] bf16 row-major; Wt: [64][K] bf16 (n-major).
__global__ __launch_bounds__(256) void gemm_mfma(
    const unsigned short* __restrict__ A, const unsigned short* __restrict__ Wt,
    float* __restrict__ C, int M, int K, int ldc, int kpb) {
    int wave = threadIdx.x >> 6, lane = threadIdx.x & 63;
    int m0 = blockIdx.x * 64;
    int kbeg = blockIdx.y * kpb;
    int kend = min(K, kbeg + kpb);
    int mrow = lane & 15, kq = lane >> 4;
    int n0 = wave * 16;
    const unsigned short* Bp = Wt + (size_t)(n0 + mrow) * K;
    float4v acc[4] = {{0.f, 0.f, 0.f, 0.f}, {0.f, 0.f, 0.f, 0.f},
                      {0.f, 0.f, 0.f, 0.f}, {0.f, 0.f, 0.f, 0.f}};
    int r0 = min(m0 + mrow, M - 1);
    int r1 = min(m0 + 16 + mrow, M - 1);
    int r2 = min(m0 + 32 + mrow, M - 1);
    int r3 = min(m0 + 48 + mrow, M - 1);
    const unsigned short* A0 = A + (size_t)r0 * K;
    const unsigned short* A1 = A + (size_t)r1 * K;
    const unsigned short* A2 = A + (size_t)r2 * K;
    const unsigned short* A3 = A + (size_t)r3 * K;
    for (int k0 = kbeg; k0 < kend; k0 += 32) {
        int kk = k0 + kq * 8;
        short8 b = *(const short8*)(Bp + kk);
        short8 a0 = *(const short8*)(A0 + kk);
        short8 a1 = *(const short8*)(A1 + kk);
        short8 a2 = *(const short8*)(A2 + kk);
        short8 a3 = *(const short8*)(A3 + kk);
        acc[0] = __builtin_amdgcn_mfma_f32_16x16x32_bf16(a0, b, acc[0], 0, 0, 0);
        acc[1] = __builtin_amdgcn_mfma_f32_16x16x32_bf16(a1, b, acc[1], 0, 0, 0);
        acc[2] = __builtin_amdgcn_mfma_f32_16x16x32_bf16(a2, b, acc[2], 0, 0, 0);
        acc[3] = __builtin_amdgcn_mfma_f32_16x16x32_bf16(a3, b, acc[3], 0, 0, 0);
    }
    int col = lane & 15, rq = lane >> 4;
#pragma unroll
    for (int mt = 0; mt < 4; mt++) {
#pragma unroll
        for (int r = 0; r < 4; r++) {
            int m = m0 + mt * 16 + rq * 4 + r;
            if (m < M) atomicAdd(&C[(size_t)m * ldc + n0 + col], acc[mt][r]);
        }
    }
}

// bf16 MFMA GEMM, f32 direct store, N-tiled via blockIdx.y, full K (layer-3 P).
__global__ __launch_bounds__(256) void gemm_mfma_store(
    const unsigned short* __restrict__ A, const unsigned short* __restrict__ Wt,
    float* __restrict__ C, int M, int K, int ldc) {
    int wave = threadIdx.x >> 6, lane = threadIdx.x & 63;
    int m0 = blockIdx.x * 64;
    int n0 = blockIdx.y * 64 + wave * 16;
    int mrow = lane & 15, kq = lane >> 4;
    const unsigned short* Bp = Wt + (size_t)(n0 + mrow) * K;
    float4v acc[4] = {{0.f, 0.f, 0.f, 0.f}, {0.f, 0.f, 0.f, 0.f},
                      {0.f, 0.f, 0.f, 0.f}, {0.f, 0.f, 0.f, 0.f}};
    int r0 = min(m0 + mrow, M - 1);
    int r1 = min(m0 + 16 + mrow, M - 1);
    int r2 = min(m0 + 32 + mrow, M - 1);
    int r3 = min(m0 + 48 + mrow, M - 1);
    const unsigned short* A0 = A + (size_t)r0 * K;
    const unsigned short* A1 = A + (size_t)r1 * K;
    const unsigned short* A2 = A + (size_t)r2 * K;
    const unsigned short* A3 = A + (size_t)r3 * K;
    for (int k0 = 0; k0 < K; k0 += 32) {
        int kk = k0 + kq * 8;
        short8 b = *(const short8*)(Bp + kk);
        short8 a0 = *(const short8*)(A0 + kk);
        short8 a1 = *(const short8*)(A1 + kk);
        short8 a2 = *(const short8*)(A2 + kk);
        short8 a3 = *(const short8*)(A3 + kk);
        acc[0] = __builtin_amdgcn_mfma_f32_16x16x32_bf16(a0, b, acc[0], 0, 0, 0);
        acc[1] = __builtin_amdgcn_mfma_f32_16x16x32_bf16(a1, b, acc[1], 0, 0, 0);
        acc[2] = __builtin_amdgcn_mfma_f32_16x16x32_bf16(a2, b, acc[2], 0, 0, 0);
        acc[3] = __builtin_amdgcn_mfma_f32_16x16x32_bf16(a3, b, acc[3], 0, 0, 0);
    }
    int col = lane & 15, rq = lane >> 4;
#pragma unroll
    for (int mt = 0; mt < 4; mt++) {
#pragma unroll
        for (int r = 0; r < 4; r++) {
            int m = m0 + mt * 16 + rq * 4 + r;
            if (m < M) C[(size_t)m * ldc + n0 + col] = acc[mt][r];
        }
    }
}

// Layer 3: y3[q] = sum_edges sum_corners w * P[s][cell*3+o] + relu(x64b[q])@w_d3 + b_d3.
__global__ __launch_bounds__(256) void conv3_reduce(
    const float* __restrict__ P,
    const float* __restrict__ wgt, const uint2* __restrict__ cells,
    const int* __restrict__ s_idx, const int* __restrict__ row_ptr,
    const unsigned short* __restrict__ hq, const float* __restrict__ wd3,
    const float* __restrict__ b3, int n, float* __restrict__ y3) {
    int wave = threadIdx.x >> 6, lane = threadIdx.x & 63;
    int q = blockIdx.x * 4 + wave;
    if (q >= n) return;
    float a0 = 0.f, a1 = 0.f, a2 = 0.f;
    int e0 = row_ptr[q], e1 = row_ptr[q + 1];
    for (int e = e0 + lane; e < e1; e += 64) {
        int s = s_idx[e];
        uint2 cp = cells[e];
        const float4* wp = (const float4*)(wgt + (size_t)e * 8);
        float4 wa = wp[0], wb = wp[1];
        const float* Ps = P + (size_t)s * 192;
        float wv[8] = {wa.x, wa.y, wa.z, wa.w, wb.x, wb.y, wb.z, wb.w};
#pragma unroll
        for (int c = 0; c < 8; c++) {
            unsigned word = (c < 4) ? cp.x : cp.y;
            int cell = (int)((word >> ((c & 3) * 8)) & 255u);
            const float* pc = Ps + cell * 3;
            a0 += wv[c] * pc[0];
            a1 += wv[c] * pc[1];
            a2 += wv[c] * pc[2];
        }
    }
    float hv = bf2f(hq[(size_t)q * 64 + lane]);
    a0 += hv * wd3[lane * 3 + 0];
    a1 += hv * wd3[lane * 3 + 1];
    a2 += hv * wd3[lane * 3 + 2];
#pragma unroll
    for (int off = 32; off > 0; off >>= 1) {
        a0 += __shfl_xor(a0, off);
        a1 += __shfl_xor(a1, off);
        a2 += __shfl_xor(a2, off);
    }
    if (lane == 0) {
        y3[(size_t)q * 3 + 0] = a0 + b3[0];
        y3[(size_t)q * 3 + 1] = a1 + b3[1];
        y3[(size_t)q * 3 + 2] = a2 + b3[2];
    }
}

__global__ void final_kernel(const float* __restrict__ pos, const float* __restrict__ pos2,
                             const float* __restrict__ y3, int n, float* __restrict__ out) {
    int i = blockIdx.x * blockDim.x + threadIdx.x;
    if (i >= n * 3) return;
    float pn = pos2[i] + y3[i] * (1.f / 128.f);
    out[i] = pn;
    out[n * 3 + i] = (pn - pos[i]) * (1.f / DT_F);
}

extern "C" void kernel_launch(void* const* d_in, const int* in_sizes, int n_in,
                              void* d_out, int out_size, void* d_ws, size_t ws_size,
                              hipStream_t stream) {
    const float* pos       = (const float*)d_in[0];
    const float* vel       = (const float*)d_in[1];
    const float* box       = (const float*)d_in[2];
    const float* box_feats = (const float*)d_in[3];
    const int*   ff_q      = (const int*)d_in[4];
    const int*   ff_s      = (const int*)d_in[5];
    const int*   fo_q      = (const int*)d_in[6];
    const int*   fo_s      = (const int*)d_in[7];
    const float* w_cf0     = (const float*)d_in[8];
    const float* w_co0     = (const float*)d_in[9];
    const float* w_d0      = (const float*)d_in[10];
    const float* b_d0      = (const float*)d_in[11];
    const float* w_c1      = (const float*)d_in[12];
    const float* w_d1      = (const float*)d_in[13];
    const float* b_d1      = (const float*)d_in[14];
    const float* w_c2      = (const float*)d_in[15];
    const float* w_d2      = (const float*)d_in[16];
    const float* b_d2      = (const float*)d_in[17];
    const float* w_c3      = (const float*)d_in[18];
    const float* w_d3      = (const float*)d_in[19];
    const float* b_d3      = (const float*)d_in[20];
    float* out = (float*)d_out;

    int n   = in_sizes[0] / 3;
    int nb  = in_sizes[2] / 3;
    int Eff = in_sizes[4];
    int Efo = in_sizes[6];

    float* base = (float*)d_ws;
    size_t off = 0;
    auto alloc = [&](size_t nf) { float* p = base + off; off += (nf + 3) & ~(size_t)3; return p; };
    float* pos2  = alloc((size_t)n * 3);
    float* fl    = alloc((size_t)n * 4);
    float* x96   = alloc((size_t)n * 96);
    float* x64a  = alloc((size_t)n * 64);
    float* x64b  = alloc((size_t)n * 64);
    float* y3    = alloc((size_t)n * 3);
    int* rp_ff   = (int*)alloc((size_t)n + 1);
    int* rp_fo   = (int*)alloc((size_t)n + 1);
    unsigned short* Wt   = (unsigned short*)alloc((size_t)65 * 96 * 64 / 2);
    unsigned short* Wt3  = (unsigned short*)alloc((size_t)192 * 64 / 2);
    unsigned short* flb  = (unsigned short*)alloc((size_t)n * 8);    // [n][16] bf16
    unsigned short* bxb  = (unsigned short*)alloc((size_t)nb * 8);   // [nb][16] bf16
    unsigned short* hb96 = (unsigned short*)alloc((size_t)n * 48);   // [n][96] bf16
    unsigned short* hb64 = (unsigned short*)alloc((size_t)n * 32);   // [n][64] bf16
    float* P3    = alloc((size_t)n * 192);
    float* wgt_ff = alloc((size_t)Eff * 8);
    uint2* cl_ff  = (uint2*)alloc((size_t)Eff * 2);
    float* wgt_fo = alloc((size_t)Efo * 8);
    uint2* cl_fo  = (uint2*)alloc((size_t)Efo * 2);
    unsigned short* Gb = (unsigned short*)(base + off);     // bf16 G (all layers)

    size_t totalF = ws_size / sizeof(float);
    size_t availF = (totalF > off) ? (totalF - off) : 0;
    auto chunkQ = [&](size_t floatsPerQ) {
        long q = (long)(availF / floatsPerQ);
        if (q < 1) q = 1;
        if (q > n) q = n;
        return (int)q;
    };

    // --- prep, CSR, edge geometry (once) ---
    prep_kernel<<<cdiv(n, 256), 256, 0, stream>>>(pos, vel, n, pos2, fl);
    row_ptr_kernel<<<cdiv(n + 1, 256), 256, 0, stream>>>(ff_q, Eff, n, rp_ff);
    row_ptr_kernel<<<cdiv(n + 1, 256), 256, 0, stream>>>(fo_q, Efo, n, rp_fo);
    edge_geom_kernel<<<cdiv(Eff, 256), 256, 0, stream>>>(pos2, pos2, ff_q, ff_s, Eff, wgt_ff, cl_ff);
    edge_geom_kernel<<<cdiv(Efo, 256), 256, 0, stream>>>(pos2, box, fo_q, fo_s, Efo, wgt_fo, cl_fo);

    // --- layer 0: both convs via MFMA build (K = 66*16 = 1056), dense folded in ---
    init_x96_kernel<<<cdiv(n * 96, 256), 256, 0, stream>>>(x96, b_d0, n);
    pad16_bf16<<<cdiv(n * 16, 256), 256, 0, stream>>>(fl, n, 4, flb);
    pad16_bf16<<<cdiv(nb * 16, 256), 256, 0, stream>>>(box_feats, nb, 3, bxb);
    {
        const int K = 66 * 16;  // 1056, multiple of 32
        int Q = chunkQ((size_t)K / 2);
        // fluid conv -> x96 cols 32:64, dense -> cols 64:96
        wt0f_kernel<<<cdiv(64 * K, 256), 256, 0, stream>>>(w_cf0, w_d0, Wt);
        for (int q0 = 0; q0 < n; q0 += Q) {
            int mc = std::min(Q, n - q0);
            build_G_mfma<16, 66><<<mc, 256, 0, stream>>>(
                flb, wgt_ff, cl_ff, ff_s, rp_ff, q0, Gb);
            gemm_mfma<<<dim3(cdiv(mc, 64), 4), 256, 0, stream>>>(
                Gb, Wt, x96 + (size_t)q0 * 96 + 32, mc, K, 96, cdiv(K / 32, 4) * 32);
        }
        // box conv -> x96 cols 0:32 (cols 32:64 of this gemm are zero-weights)
        wt0b_kernel<<<cdiv(64 * K, 256), 256, 0, stream>>>(w_co0, Wt);
        for (int q0 = 0; q0 < n; q0 += Q) {
            int mc = std::min(Q, n - q0);
            build_G_mfma<16, 66><<<mc, 256, 0, stream>>>(
                bxb, wgt_fo, cl_fo, fo_s, rp_fo, q0, Gb);
            gemm_mfma<<<dim3(cdiv(mc, 64), 4), 256, 0, stream>>>(
                Gb, Wt, x96 + (size_t)q0 * 96, mc, K, 96, cdiv(K / 32, 4) * 32);
        }
    }

    // --- layer 1: 96 -> 64, MFMA build + MFMA gemm (round-10 config) ---
    {
        const int K = 65 * 96;
        wt_kernel<<<cdiv(64 * K, 256), 256, 0, stream>>>(w_c1, w_d1, 96, 64, K, Wt);
        init_out_kernel<<<cdiv(n * 64, 256), 256, 0, stream>>>(x64a, b_d1, nullptr, n, 64, 64);
        relu_bf16_kernel<<<cdiv(n * 96, 256), 256, 0, stream>>>(x96, n * 96, hb96);
        int Q = chunkQ((size_t)K / 2);
        for (int q0 = 0; q0 < n; q0 += Q) {
            int mc = std::min(Q, n - q0);
            build_G_mfma<96, 65><<<mc, 256, 0, stream>>>(
                hb96, wgt_ff, cl_ff, ff_s, rp_ff, q0, Gb);
            gemm_mfma<<<dim3(cdiv(mc, 64), 4), 256, 0, stream>>>(
                Gb, Wt, x64a + (size_t)q0 * 64, mc, K, 64, cdiv(K / 32, 4) * 32);
        }
    }

    // --- layer 2: 64 -> 64, residual, MFMA build + MFMA gemm ---
    {
        const int K = 65 * 64;
        wt_kernel<<<cdiv(64 * K, 256), 256, 0, stream>>>(w_c2, w_d2, 64, 64, K, Wt);
        init_out_kernel<<<cdiv(n * 64, 256), 256, 0, stream>>>(x64b, b_d2, x64a, n, 64, 64);
        relu_bf16_kernel<<<cdiv(n * 64, 256), 256, 0, stream>>>(x64a, n * 64, hb64);
        int Q = chunkQ((size_t)K / 2);
        for (int q0 = 0; q0 < n; q0 += Q) {
            int mc = std::min(Q, n - q0);
            build_G_mfma<64, 65><<<mc, 256, 0, stream>>>(
                hb64, wgt_ff, cl_ff, ff_s, rp_ff, q0, Gb);
            gemm_mfma<<<dim3(cdiv(mc, 64), 4), 256, 0, stream>>>(
                Gb, Wt, x64b + (size_t)q0 * 64, mc, K, 64, cdiv(K / 32, 4) * 32);
        }
    }

    // --- layer 3: 64 -> 3 via P-trick (3-channel P stays cache-resident) ---
    {
        relu_bf16_kernel<<<cdiv(n * 64, 256), 256, 0, stream>>>(x64b, n * 64, hb64);
        wt3_kernel<<<cdiv(192 * 64, 256), 256, 0, stream>>>(w_c3, Wt3);
        gemm_mfma_store<<<dim3(cdiv(n, 64), 3), 256, 0, stream>>>(hb64, Wt3, P3, n, 64, 192);
        conv3_reduce<<<cdiv(n, 4), 256, 0, stream>>>(
            P3, wgt_ff, cl_ff, ff_s, rp_ff, hb64, w_d3, b_d3, n, y3);
    }

    final_kernel<<<cdiv(n * 3, 256), 256, 0, stream>>>(pos, pos2, y3, n, out);
}

// Round 13
// 728.990 us; speedup vs baseline: 1.2470x; 1.1367x over previous
//
#include <hip/hip_runtime.h>
#include <algorithm>

#define DT_F 0.02f
#define INV_R (1.0f / 0.1125f)

typedef __attribute__((ext_vector_type(8))) short short8;
typedef __attribute__((ext_vector_type(4))) float float4v;

static inline int cdiv(int a, int b) { return (a + b - 1) / b; }

__device__ __forceinline__ float sgnf(float v) {
    return (v > 0.f) ? 1.f : ((v < 0.f) ? -1.f : 0.f);
}

__device__ __forceinline__ unsigned short f2bf(float f) {
    union { float f; unsigned u; } v; v.f = f;
    return (unsigned short)((v.u + 0x7fffu + ((v.u >> 16) & 1u)) >> 16);
}
__device__ __forceinline__ float bf2f(unsigned short h) {
    union { unsigned u; float f; } v; v.u = ((unsigned)h) << 16;
    return v.f;
}

// Exact port of reference ball_to_cube (f32).
__device__ __forceinline__ void ball_to_cube_dev(float x, float y, float z,
                                                 float& ox, float& oy, float& oz) {
    const float eps = 1e-12f;
    float sq = x * x + y * y + z * z;
    float nrm = sqrtf(sq + eps);
    float xy2 = x * x + y * y;
    bool cap = 1.25f * z * z > xy2;
    float s_cap = sqrtf(3.f * nrm / (nrm + fabsf(z) + eps));
    float s_side = nrm / sqrtf(xy2 + eps);
    float s = cap ? s_cap : s_side;
    float xc = x * s, yc = y * s;
    float zc = cap ? sgnf(z) * nrm : 1.5f * z;
    if (!(sq > eps)) { xc = 0.f; yc = 0.f; zc = 0.f; }
    float rxy = sqrtf(xc * xc + yc * yc + eps);
    bool xbig = fabsf(yc) <= fabsf(xc);
    float dx = (fabsf(xc) > eps) ? xc : 1.f;
    float dy = (fabsf(yc) > eps) ? yc : 1.f;
    const float c4pi = 1.27323954473516276f;  // 4/pi
    float tx = sgnf(xc) * rxy, ty = sgnf(yc) * rxy;
    float xq = xbig ? tx : ty * c4pi * atanf(xc / dy);
    float yq = xbig ? tx * c4pi * atanf(yc / dx) : ty;
    if (!(xc * xc + yc * yc > eps)) { xq = 0.f; yq = 0.f; }
    ox = xq; oy = yq; oz = zc;
}

__global__ void prep_kernel(const float* __restrict__ pos, const float* __restrict__ vel,
                            int n, float* __restrict__ pos2, float* __restrict__ fl) {
    int i = blockIdx.x * blockDim.x + threadIdx.x;
    if (i >= n) return;
    float v0 = vel[i * 3 + 0], v1 = vel[i * 3 + 1], v2 = vel[i * 3 + 2];
    float u0 = v0, u1 = v1 + DT_F * (-9.81f), u2 = v2;
    pos2[i * 3 + 0] = pos[i * 3 + 0] + DT_F * (u0 + v0) * 0.5f;
    pos2[i * 3 + 1] = pos[i * 3 + 1] + DT_F * (u1 + v1) * 0.5f;
    pos2[i * 3 + 2] = pos[i * 3 + 2] + DT_F * (u2 + v2) * 0.5f;
    fl[i * 4 + 0] = 1.f;
    fl[i * 4 + 1] = u0;
    fl[i * 4 + 2] = u1;
    fl[i * 4 + 3] = u2;
}

__global__ void row_ptr_kernel(const int* __restrict__ q_idx, int E, int nq,
                               int* __restrict__ row_ptr) {
    int q = blockIdx.x * blockDim.x + threadIdx.x;
    if (q > nq) return;
    int lo = 0, hi = E;
    while (lo < hi) {
        int mid = (lo + hi) >> 1;
        if (q_idx[mid] < q) lo = mid + 1; else hi = mid;
    }
    row_ptr[q] = lo;
}

// Per-edge geometry once; ix clamped to [0,2] => 8 distinct corners.
// Outputs: wgt[e][8] (win folded), cells[e] = 8 packed cell bytes.
__global__ void edge_geom_kernel(const float* __restrict__ posq, const float* __restrict__ poss,
                                 const int* __restrict__ q_idx, const int* __restrict__ s_idx,
                                 int E, float* __restrict__ wgt, uint2* __restrict__ cells) {
    int e = blockIdx.x * blockDim.x + threadIdx.x;
    if (e >= E) return;
    int q = q_idx[e], s = s_idx[e];
    float dx = (poss[s * 3 + 0] - posq[q * 3 + 0]) * INV_R;
    float dy = (poss[s * 3 + 1] - posq[q * 3 + 1]) * INV_R;
    float dz = (poss[s * 3 + 2] - posq[q * 3 + 2]) * INV_R;
    float r2 = dx * dx + dy * dy + dz * dz;
    float w1 = 1.f - r2;
    float win = fminf(fmaxf(w1 * w1 * w1, 0.f), 1.f);
    float bx, by, bz;
    ball_to_cube_dev(dx, dy, dz, bx, by, bz);
    float gx = (bx + 1.f) * 1.5f, gy = (by + 1.f) * 1.5f, gz = (bz + 1.f) * 1.5f;
    int ix = min(max((int)floorf(gx), 0), 2);
    int iy = min(max((int)floorf(gy), 0), 2);
    int iz = min(max((int)floorf(gz), 0), 2);
    float fx = gx - (float)ix, fy = gy - (float)iy, fz = gz - (float)iz;
    float wv[8];
    unsigned int cl[8];
#pragma unroll
    for (int c = 0; c < 8; c++) {
        int cbx = (c >> 2) & 1, cby = (c >> 1) & 1, cbz = c & 1;
        int jx = ix + cbx, jy = iy + cby, jz = iz + cbz;
        cl[c] = (unsigned int)((jx * 4 + jy) * 4 + jz);
        wv[c] = win * (cbx ? fx : 1.f - fx) * (cby ? fy : 1.f - fy) * (cbz ? fz : 1.f - fz);
    }
    float4* wp = (float4*)(wgt + (size_t)e * 8);
    wp[0] = make_float4(wv[0], wv[1], wv[2], wv[3]);
    wp[1] = make_float4(wv[4], wv[5], wv[6], wv[7]);
    uint2 cp;
    cp.x = cl[0] | (cl[1] << 8) | (cl[2] << 16) | (cl[3] << 24);
    cp.y = cl[4] | (cl[5] << 8) | (cl[6] << 16) | (cl[7] << 24);
    cells[e] = cp;
}

// x96 init: cols 0:64 = 0 (conv targets), cols 64:96 = b_d0 (dense bias).
__global__ void init_x96_kernel(float* __restrict__ x96, const float* __restrict__ b0, int n) {
    int i = blockIdx.x * blockDim.x + threadIdx.x;
    if (i >= n * 96) return;
    int o = i % 96;
    x96[i] = (o >= 64) ? b0[o - 64] : 0.f;
}

// C[q,o] = bias[o] (+resid[q,o]) (pre-init for atomic split-K).
__global__ void init_out_kernel(float* __restrict__ C, const float* __restrict__ bias,
                                const float* __restrict__ resid, int n, int co, int ldc) {
    int i = blockIdx.x * blockDim.x + threadIdx.x;
    if (i >= n * co) return;
    int q = i / co, o = i - q * co;
    float v = bias ? bias[o] : 0.f;
    if (resid) v += resid[(size_t)q * ldc + o];
    C[(size_t)q * ldc + o] = v;
}

// Wt[n][k] = bf16(W[k][n]) with W = [w_c (64*ci rows) ; w_d (ci rows)], K = 65*ci.
__global__ void wt_kernel(const float* __restrict__ wc, const float* __restrict__ wd,
                          int ci, int co, int K, unsigned short* __restrict__ Wt) {
    int i = blockIdx.x * blockDim.x + threadIdx.x;
    if (i >= co * K) return;
    int n = i / K, k = i - n * K;
    float v = (k < 64 * ci) ? wc[(size_t)k * co + n] : wd[(size_t)(k - 64 * ci) * co + n];
    Wt[i] = f2bf(v);
}

// L0 fluid Wt: [64][1056]; slot=k>>4, c=k&15. Out cols 0:32 = conv w_cf0 (CI=4, CO=32),
// cols 32:64 = dense w_d0 (slot 64). Slots padded with zeros (c>=CI, slot 65).
__global__ void wt0f_kernel(const float* __restrict__ wcf, const float* __restrict__ wd,
                            unsigned short* __restrict__ Wt) {
    int i = blockIdx.x * blockDim.x + threadIdx.x;
    if (i >= 64 * 1056) return;
    int nrow = i / 1056, k = i - nrow * 1056;
    int slot = k >> 4, c = k & 15;
    float v = 0.f;
    if (nrow < 32) {
        if (slot < 64 && c < 4) v = wcf[((size_t)slot * 4 + c) * 32 + nrow];
    } else {
        if (slot == 64 && c < 4) v = wd[c * 32 + (nrow - 32)];
    }
    Wt[i] = f2bf(v);
}

// L0 box Wt: [64][1056]; out cols 0:32 = conv w_co0 (CI=3); cols 32:64 = 0.
__global__ void wt0b_kernel(const float* __restrict__ wco, unsigned short* __restrict__ Wt) {
    int i = blockIdx.x * blockDim.x + threadIdx.x;
    if (i >= 64 * 1056) return;
    int nrow = i / 1056, k = i - nrow * 1056;
    int slot = k >> 4, c = k & 15;
    float v = 0.f;
    if (nrow < 32 && slot < 64 && c < 3) v = wco[((size_t)slot * 3 + c) * 32 + nrow];
    Wt[i] = f2bf(v);
}

// Wt3[j=cell*3+o][k] = bf16(w_c3[cell][k][o]); 192 rows x 64 cols.
__global__ void wt3_kernel(const float* __restrict__ wc, unsigned short* __restrict__ Wt) {
    int i = blockIdx.x * blockDim.x + threadIdx.x;
    if (i >= 192 * 64) return;
    int j = i >> 6, k = i & 63;
    int cell = j / 3, o = j - cell * 3;
    Wt[i] = f2bf(wc[((size_t)cell * 64 + k) * 3 + o]);
}

// h = bf16(relu(x)), flat n elems.
__global__ void relu_bf16_kernel(const float* __restrict__ x, int n,
                                 unsigned short* __restrict__ h) {
    int i = blockIdx.x * blockDim.x + threadIdx.x;
    if (i < n) h[i] = f2bf(fmaxf(x[i], 0.f));
}

// dst[q][0..15] = bf16(src[q][0..c-1]) zero-padded to 16.
__global__ void pad16_bf16(const float* __restrict__ src, int n, int c,
                           unsigned short* __restrict__ dst) {
    int i = blockIdx.x * blockDim.x + threadIdx.x;
    if (i >= n * 16) return;
    int q = i >> 4, k = i & 15;
    dst[i] = (k < c) ? f2bf(src[q * c + k]) : (unsigned short)0;
}

// G build via per-query MFMA: G(64xCIN) = S^T(64xE) . F(ExCIN), chunks of 64 edges.
// S[cell][e] bf16 LDS (zeroed per chunk; every (cell,e) unique -> plain stores, no races).
// Ft[ch][e] bf16 LDS staged from bf16 features hb (row stride CIN). LDK=72 pad.
// Wave w owns cells [16w,16w+16). G out bf16 [Q][SLOTS][CIN]; slot 64 = hb[q],
// slots >= 65 zero (K padding so 16*SLOTS is a multiple of 32).
template <int CIN, int SLOTS>
__global__ __launch_bounds__(256) void build_G_mfma(
    const unsigned short* __restrict__ hb,
    const float* __restrict__ wgt, const uint2* __restrict__ cells,
    const int* __restrict__ s_idx, const int* __restrict__ row_ptr,
    int q0, unsigned short* __restrict__ G) {
    constexpr int LDK = 72;
    constexpr int CP = CIN / 2;
    constexpr int NT = CIN / 16;
    __shared__ unsigned short S[64 * LDK];
    __shared__ unsigned short Ft[CIN * LDK];
    int lq = blockIdx.x, q = q0 + lq, t = threadIdx.x;
    int wave = t >> 6, lane = t & 63;
    int e0 = row_ptr[q], e1 = row_ptr[q + 1];
    int nE = e1 - e0;
    float4v acc[NT];
#pragma unroll
    for (int i = 0; i < NT; i++) acc[i] = (float4v){0.f, 0.f, 0.f, 0.f};

    for (int c0 = 0; c0 < nE; c0 += 64) {
        int cnt = min(64, nE - c0);
        __syncthreads();  // prior chunk's MFMA reads done before overwrite
        for (int i = t; i < 64 * LDK / 2; i += 256) ((unsigned int*)S)[i] = 0u;
        for (int i = t; i < 64 * CP; i += 256) {
            int e = i / CP, cp = i - e * CP;
            unsigned v = 0u;
            if (e < cnt) {
                int s = s_idx[e0 + c0 + e];
                v = ((const unsigned int*)hb)[(size_t)s * CP + cp];
            }
            Ft[(2 * cp) * LDK + e] = (unsigned short)(v & 0xffffu);
            Ft[(2 * cp + 1) * LDK + e] = (unsigned short)(v >> 16);
        }
        {
            int e = t >> 2, cpair = t & 3;
            if (e < cnt) {
                int ee = e0 + c0 + e;
                uint2 cp = cells[ee];
                float w0 = wgt[(size_t)ee * 8 + cpair * 2];
                float w1 = wgt[(size_t)ee * 8 + cpair * 2 + 1];
                unsigned word = (cpair < 2) ? cp.x : cp.y;
                int sh = (cpair & 1) * 16;
                int cell0 = (int)((word >> sh) & 255u);
                int cell1 = (int)((word >> (sh + 8)) & 255u);
                S[cell0 * LDK + e] = f2bf(w0);
                S[cell1 * LDK + e] = f2bf(w1);
            }
        }
        __syncthreads();
        int kq = lane >> 4, mrow = lane & 15;
#pragma unroll
        for (int ks = 0; ks < 2; ks++) {
            int kk = ks * 32 + kq * 8;
            short8 a = *(const short8*)(S + (wave * 16 + mrow) * LDK + kk);
#pragma unroll
            for (int nt = 0; nt < NT; nt++) {
                short8 b = *(const short8*)(Ft + (nt * 16 + mrow) * LDK + kk);
                acc[nt] = __builtin_amdgcn_mfma_f32_16x16x32_bf16(a, b, acc[nt], 0, 0, 0);
            }
        }
    }
    unsigned short* Go = G + (size_t)lq * (size_t)(SLOTS * CIN);
    int col = lane & 15, rq = lane >> 4;
#pragma unroll
    for (int nt = 0; nt < NT; nt++) {
#pragma unroll
        for (int r = 0; r < 4; r++) {
            int cell = wave * 16 + rq * 4 + r;
            Go[cell * CIN + nt * 16 + col] = f2bf(acc[nt][r]);
        }
    }
    if (t < CP) {
        ((unsigned int*)(Go + 64 * CIN))[t] = ((const unsigned int*)hb)[(size_t)q * CP + t];
    }
    if (SLOTS > 65) {
        if (t < (SLOTS - 65) * CP) ((unsigned int*)(Go + 65 * CIN))[t] = 0u;
    }
}

// bf16 MFMA GEMM, split-K atomics, WIDE wave tile: each wave computes 64 M-rows x
// full N=64 (4 a-frags x 4 b-frags = 16 MFMAs per 32-K step, 8 loads in flight).
// Block = 4 waves = 256 M-rows. A: [M][K] bf16; Wt: [64][K] bf16 (n-major).
__global__ __launch_bounds__(256) void gemm_mfma(
    const unsigned short* __restrict__ A, const unsigned short* __restrict__ Wt,
    float* __restrict__ C, int M, int K, int ldc, int kpb) {
    int wave = threadIdx.x >> 6, lane = threadIdx.x & 63;
    int m0 = blockIdx.x * 256 + wave * 64;
    int kbeg = blockIdx.y * kpb;
    int kend = min(K, kbeg + kpb);
    int mrow = lane & 15, kq = lane >> 4;
    const unsigned short* B0 = Wt + (size_t)(0 + mrow) * K;
    const unsigned short* B1 = Wt + (size_t)(16 + mrow) * K;
    const unsigned short* B2 = Wt + (size_t)(32 + mrow) * K;
    const unsigned short* B3 = Wt + (size_t)(48 + mrow) * K;
    float4v acc[4][4];
#pragma unroll
    for (int i = 0; i < 4; i++)
#pragma unroll
        for (int j = 0; j < 4; j++) acc[i][j] = (float4v){0.f, 0.f, 0.f, 0.f};
    int r0 = min(m0 + mrow, M - 1);
    int r1 = min(m0 + 16 + mrow, M - 1);
    int r2 = min(m0 + 32 + mrow, M - 1);
    int r3 = min(m0 + 48 + mrow, M - 1);
    const unsigned short* A0 = A + (size_t)r0 * K;
    const unsigned short* A1 = A + (size_t)r1 * K;
    const unsigned short* A2 = A + (size_t)r2 * K;
    const unsigned short* A3 = A + (size_t)r3 * K;
    for (int k0 = kbeg; k0 < kend; k0 += 32) {
        int kk = k0 + kq * 8;
        short8 b0 = *(const short8*)(B0 + kk);
        short8 b1 = *(const short8*)(B1 + kk);
        short8 b2 = *(const short8*)(B2 + kk);
        short8 b3 = *(const short8*)(B3 + kk);
        short8 a0 = *(const short8*)(A0 + kk);
        short8 a1 = *(const short8*)(A1 + kk);
        short8 a2 = *(const short8*)(A2 + kk);
        short8 a3 = *(const short8*)(A3 + kk);
        acc[0][0] = __builtin_amdgcn_mfma_f32_16x16x32_bf16(a0, b0, acc[0][0], 0, 0, 0);
        acc[0][1] = __builtin_amdgcn_mfma_f32_16x16x32_bf16(a0, b1, acc[0][1], 0, 0, 0);
        acc[0][2] = __builtin_amdgcn_mfma_f32_16x16x32_bf16(a0, b2, acc[0][2], 0, 0, 0);
        acc[0][3] = __builtin_amdgcn_mfma_f32_16x16x32_bf16(a0, b3, acc[0][3], 0, 0, 0);
        acc[1][0] = __builtin_amdgcn_mfma_f32_16x16x32_bf16(a1, b0, acc[1][0], 0, 0, 0);
        acc[1][1] = __builtin_amdgcn_mfma_f32_16x16x32_bf16(a1, b1, acc[1][1], 0, 0, 0);
        acc[1][2] = __builtin_amdgcn_mfma_f32_16x16x32_bf16(a1, b2, acc[1][2], 0, 0, 0);
        acc[1][3] = __builtin_amdgcn_mfma_f32_16x16x32_bf16(a1, b3, acc[1][3], 0, 0, 0);
        acc[2][0] = __builtin_amdgcn_mfma_f32_16x16x32_bf16(a2, b0, acc[2][0], 0, 0, 0);
        acc[2][1] = __builtin_amdgcn_mfma_f32_16x16x32_bf16(a2, b1, acc[2][1], 0, 0, 0);
        acc[2][2] = __builtin_amdgcn_mfma_f32_16x16x32_bf16(a2, b2, acc[2][2], 0, 0, 0);
        acc[2][3] = __builtin_amdgcn_mfma_f32_16x16x32_bf16(a2, b3, acc[2][3], 0, 0, 0);
        acc[3][0] = __builtin_amdgcn_mfma_f32_16x16x32_bf16(a3, b0, acc[3][0], 0, 0, 0);
        acc[3][1] = __builtin_amdgcn_mfma_f32_16x16x32_bf16(a3, b1, acc[3][1], 0, 0, 0);
        acc[3][2] = __builtin_amdgcn_mfma_f32_16x16x32_bf16(a3, b2, acc[3][2], 0, 0, 0);
        acc[3][3] = __builtin_amdgcn_mfma_f32_16x16x32_bf16(a3, b3, acc[3][3], 0, 0, 0);
    }
    int col = lane & 15, rq = lane >> 4;
#pragma unroll
    for (int mt = 0; mt < 4; mt++) {
#pragma unroll
        for (int r = 0; r < 4; r++) {
            int m = m0 + mt * 16 + rq * 4 + r;
            if (m < M) {
#pragma unroll
                for (int nt = 0; nt < 4; nt++)
                    atomicAdd(&C[(size_t)m * ldc + nt * 16 + col], acc[mt][nt][r]);
            }
        }
    }
}

// bf16 MFMA GEMM, f32 direct store, N-tiled via blockIdx.y, full K (layer-3 P).
__global__ __launch_bounds__(256) void gemm_mfma_store(
    const unsigned short* __restrict__ A, const unsigned short* __restrict__ Wt,
    float* __restrict__ C, int M, int K, int ldc) {
    int wave = threadIdx.x >> 6, lane = threadIdx.x & 63;
    int m0 = blockIdx.x * 64;
    int n0 = blockIdx.y * 64 + wave * 16;
    int mrow = lane & 15, kq = lane >> 4;
    const unsigned short* Bp = Wt + (size_t)(n0 + mrow) * K;
    float4v acc[4] = {{0.f, 0.f, 0.f, 0.f}, {0.f, 0.f, 0.f, 0.f},
                      {0.f, 0.f, 0.f, 0.f}, {0.f, 0.f, 0.f, 0.f}};
    int r0 = min(m0 + mrow, M - 1);
    int r1 = min(m0 + 16 + mrow, M - 1);
    int r2 = min(m0 + 32 + mrow, M - 1);
    int r3 = min(m0 + 48 + mrow, M - 1);
    const unsigned short* A0 = A + (size_t)r0 * K;
    const unsigned short* A1 = A + (size_t)r1 * K;
    const unsigned short* A2 = A + (size_t)r2 * K;
    const unsigned short* A3 = A + (size_t)r3 * K;
    for (int k0 = 0; k0 < K; k0 += 32) {
        int kk = k0 + kq * 8;
        short8 b = *(const short8*)(Bp + kk);
        short8 a0 = *(const short8*)(A0 + kk);
        short8 a1 = *(const short8*)(A1 + kk);
        short8 a2 = *(const short8*)(A2 + kk);
        short8 a3 = *(const short8*)(A3 + kk);
        acc[0] = __builtin_amdgcn_mfma_f32_16x16x32_bf16(a0, b, acc[0], 0, 0, 0);
        acc[1] = __builtin_amdgcn_mfma_f32_16x16x32_bf16(a1, b, acc[1], 0, 0, 0);
        acc[2] = __builtin_amdgcn_mfma_f32_16x16x32_bf16(a2, b, acc[2], 0, 0, 0);
        acc[3] = __builtin_amdgcn_mfma_f32_16x16x32_bf16(a3, b, acc[3], 0, 0, 0);
    }
    int col = lane & 15, rq = lane >> 4;
#pragma unroll
    for (int mt = 0; mt < 4; mt++) {
#pragma unroll
        for (int r = 0; r < 4; r++) {
            int m = m0 + mt * 16 + rq * 4 + r;
            if (m < M) C[(size_t)m * ldc + n0 + col] = acc[mt][r];
        }
    }
}

// Layer 3: y3[q] = sum_edges sum_corners w * P[s][cell*3+o] + relu(x64b[q])@w_d3 + b_d3.
__global__ __launch_bounds__(256) void conv3_reduce(
    const float* __restrict__ P,
    const float* __restrict__ wgt, const uint2* __restrict__ cells,
    const int* __restrict__ s_idx, const int* __restrict__ row_ptr,
    const unsigned short* __restrict__ hq, const float* __restrict__ wd3,
    const float* __restrict__ b3, int n, float* __restrict__ y3) {
    int wave = threadIdx.x >> 6, lane = threadIdx.x & 63;
    int q = blockIdx.x * 4 + wave;
    if (q >= n) return;
    float a0 = 0.f, a1 = 0.f, a2 = 0.f;
    int e0 = row_ptr[q], e1 = row_ptr[q + 1];
    for (int e = e0 + lane; e < e1; e += 64) {
        int s = s_idx[e];
        uint2 cp = cells[e];
        const float4* wp = (const float4*)(wgt + (size_t)e * 8);
        float4 wa = wp[0], wb = wp[1];
        const float* Ps = P + (size_t)s * 192;
        float wv[8] = {wa.x, wa.y, wa.z, wa.w, wb.x, wb.y, wb.z, wb.w};
#pragma unroll
        for (int c = 0; c < 8; c++) {
            unsigned word = (c < 4) ? cp.x : cp.y;
            int cell = (int)((word >> ((c & 3) * 8)) & 255u);
            const float* pc = Ps + cell * 3;
            a0 += wv[c] * pc[0];
            a1 += wv[c] * pc[1];
            a2 += wv[c] * pc[2];
        }
    }
    float hv = bf2f(hq[(size_t)q * 64 + lane]);
    a0 += hv * wd3[lane * 3 + 0];
    a1 += hv * wd3[lane * 3 + 1];
    a2 += hv * wd3[lane * 3 + 2];
#pragma unroll
    for (int off = 32; off > 0; off >>= 1) {
        a0 += __shfl_xor(a0, off);
        a1 += __shfl_xor(a1, off);
        a2 += __shfl_xor(a2, off);
    }
    if (lane == 0) {
        y3[(size_t)q * 3 + 0] = a0 + b3[0];
        y3[(size_t)q * 3 + 1] = a1 + b3[1];
        y3[(size_t)q * 3 + 2] = a2 + b3[2];
    }
}

__global__ void final_kernel(const float* __restrict__ pos, const float* __restrict__ pos2,
                             const float* __restrict__ y3, int n, float* __restrict__ out) {
    int i = blockIdx.x * blockDim.x + threadIdx.x;
    if (i >= n * 3) return;
    float pn = pos2[i] + y3[i] * (1.f / 128.f);
    out[i] = pn;
    out[n * 3 + i] = (pn - pos[i]) * (1.f / DT_F);
}

extern "C" void kernel_launch(void* const* d_in, const int* in_sizes, int n_in,
                              void* d_out, int out_size, void* d_ws, size_t ws_size,
                              hipStream_t stream) {
    const float* pos       = (const float*)d_in[0];
    const float* vel       = (const float*)d_in[1];
    const float* box       = (const float*)d_in[2];
    const float* box_feats = (const float*)d_in[3];
    const int*   ff_q      = (const int*)d_in[4];
    const int*   ff_s      = (const int*)d_in[5];
    const int*   fo_q      = (const int*)d_in[6];
    const int*   fo_s      = (const int*)d_in[7];
    const float* w_cf0     = (const float*)d_in[8];
    const float* w_co0     = (const float*)d_in[9];
    const float* w_d0      = (const float*)d_in[10];
    const float* b_d0      = (const float*)d_in[11];
    const float* w_c1      = (const float*)d_in[12];
    const float* w_d1      = (const float*)d_in[13];
    const float* b_d1      = (const float*)d_in[14];
    const float* w_c2      = (const float*)d_in[15];
    const float* w_d2      = (const float*)d_in[16];
    const float* b_d2      = (const float*)d_in[17];
    const float* w_c3      = (const float*)d_in[18];
    const float* w_d3      = (const float*)d_in[19];
    const float* b_d3      = (const float*)d_in[20];
    float* out = (float*)d_out;

    int n   = in_sizes[0] / 3;
    int nb  = in_sizes[2] / 3;
    int Eff = in_sizes[4];
    int Efo = in_sizes[6];

    float* base = (float*)d_ws;
    size_t off = 0;
    auto alloc = [&](size_t nf) { float* p = base + off; off += (nf + 3) & ~(size_t)3; return p; };
    float* pos2  = alloc((size_t)n * 3);
    float* fl    = alloc((size_t)n * 4);
    float* x96   = alloc((size_t)n * 96);
    float* x64a  = alloc((size_t)n * 64);
    float* x64b  = alloc((size_t)n * 64);
    float* y3    = alloc((size_t)n * 3);
    int* rp_ff   = (int*)alloc((size_t)n + 1);
    int* rp_fo   = (int*)alloc((size_t)n + 1);
    unsigned short* Wt   = (unsigned short*)alloc((size_t)65 * 96 * 64 / 2);
    unsigned short* Wt3  = (unsigned short*)alloc((size_t)192 * 64 / 2);
    unsigned short* flb  = (unsigned short*)alloc((size_t)n * 8);    // [n][16] bf16
    unsigned short* bxb  = (unsigned short*)alloc((size_t)nb * 8);   // [nb][16] bf16
    unsigned short* hb96 = (unsigned short*)alloc((size_t)n * 48);   // [n][96] bf16
    unsigned short* hb64 = (unsigned short*)alloc((size_t)n * 32);   // [n][64] bf16
    float* P3    = alloc((size_t)n * 192);
    float* wgt_ff = alloc((size_t)Eff * 8);
    uint2* cl_ff  = (uint2*)alloc((size_t)Eff * 2);
    float* wgt_fo = alloc((size_t)Efo * 8);
    uint2* cl_fo  = (uint2*)alloc((size_t)Efo * 2);
    unsigned short* Gb = (unsigned short*)(base + off);     // bf16 G (all layers)

    size_t totalF = ws_size / sizeof(float);
    size_t availF = (totalF > off) ? (totalF - off) : 0;
    auto chunkQ = [&](size_t floatsPerQ) {
        long q = (long)(availF / floatsPerQ);
        if (q < 1) q = 1;
        if (q > n) q = n;
        return (int)q;
    };

    // --- prep, CSR, edge geometry (once) ---
    prep_kernel<<<cdiv(n, 256), 256, 0, stream>>>(pos, vel, n, pos2, fl);
    row_ptr_kernel<<<cdiv(n + 1, 256), 256, 0, stream>>>(ff_q, Eff, n, rp_ff);
    row_ptr_kernel<<<cdiv(n + 1, 256), 256, 0, stream>>>(fo_q, Efo, n, rp_fo);
    edge_geom_kernel<<<cdiv(Eff, 256), 256, 0, stream>>>(pos2, pos2, ff_q, ff_s, Eff, wgt_ff, cl_ff);
    edge_geom_kernel<<<cdiv(Efo, 256), 256, 0, stream>>>(pos2, box, fo_q, fo_s, Efo, wgt_fo, cl_fo);

    // --- layer 0: both convs via MFMA build (K = 66*16 = 1056), dense folded in ---
    init_x96_kernel<<<cdiv(n * 96, 256), 256, 0, stream>>>(x96, b_d0, n);
    pad16_bf16<<<cdiv(n * 16, 256), 256, 0, stream>>>(fl, n, 4, flb);
    pad16_bf16<<<cdiv(nb * 16, 256), 256, 0, stream>>>(box_feats, nb, 3, bxb);
    {
        const int K = 66 * 16;  // 1056, multiple of 32
        int Q = chunkQ((size_t)K / 2);
        // fluid conv -> x96 cols 32:64, dense -> cols 64:96
        wt0f_kernel<<<cdiv(64 * K, 256), 256, 0, stream>>>(w_cf0, w_d0, Wt);
        for (int q0 = 0; q0 < n; q0 += Q) {
            int mc = std::min(Q, n - q0);
            build_G_mfma<16, 66><<<mc, 256, 0, stream>>>(
                flb, wgt_ff, cl_ff, ff_s, rp_ff, q0, Gb);
            gemm_mfma<<<dim3(cdiv(mc, 256), 4), 256, 0, stream>>>(
                Gb, Wt, x96 + (size_t)q0 * 96 + 32, mc, K, 96, cdiv(K / 32, 4) * 32);
        }
        // box conv -> x96 cols 0:32 (cols 32:64 of this gemm are zero-weights)
        wt0b_kernel<<<cdiv(64 * K, 256), 256, 0, stream>>>(w_co0, Wt);
        for (int q0 = 0; q0 < n; q0 += Q) {
            int mc = std::min(Q, n - q0);
            build_G_mfma<16, 66><<<mc, 256, 0, stream>>>(
                bxb, wgt_fo, cl_fo, fo_s, rp_fo, q0, Gb);
            gemm_mfma<<<dim3(cdiv(mc, 256), 4), 256, 0, stream>>>(
                Gb, Wt, x96 + (size_t)q0 * 96, mc, K, 96, cdiv(K / 32, 4) * 32);
        }
    }

    // --- layer 1: 96 -> 64, MFMA build + wide MFMA gemm (split-K 8) ---
    {
        const int K = 65 * 96;
        wt_kernel<<<cdiv(64 * K, 256), 256, 0, stream>>>(w_c1, w_d1, 96, 64, K, Wt);
        init_out_kernel<<<cdiv(n * 64, 256), 256, 0, stream>>>(x64a, b_d1, nullptr, n, 64, 64);
        relu_bf16_kernel<<<cdiv(n * 96, 256), 256, 0, stream>>>(x96, n * 96, hb96);
        int Q = chunkQ((size_t)K / 2);
        for (int q0 = 0; q0 < n; q0 += Q) {
            int mc = std::min(Q, n - q0);
            build_G_mfma<96, 65><<<mc, 256, 0, stream>>>(
                hb96, wgt_ff, cl_ff, ff_s, rp_ff, q0, Gb);
            gemm_mfma<<<dim3(cdiv(mc, 256), 8), 256, 0, stream>>>(
                Gb, Wt, x64a + (size_t)q0 * 64, mc, K, 64, cdiv(K / 32, 8) * 32);
        }
    }

    // --- layer 2: 64 -> 64, residual, MFMA build + wide MFMA gemm (split-K 8) ---
    {
        const int K = 65 * 64;
        wt_kernel<<<cdiv(64 * K, 256), 256, 0, stream>>>(w_c2, w_d2, 64, 64, K, Wt);
        init_out_kernel<<<cdiv(n * 64, 256), 256, 0, stream>>>(x64b, b_d2, x64a, n, 64, 64);
        relu_bf16_kernel<<<cdiv(n * 64, 256), 256, 0, stream>>>(x64a, n * 64, hb64);
        int Q = chunkQ((size_t)K / 2);
        for (int q0 = 0; q0 < n; q0 += Q) {
            int mc = std::min(Q, n - q0);
            build_G_mfma<64, 65><<<mc, 256, 0, stream>>>(
                hb64, wgt_ff, cl_ff, ff_s, rp_ff, q0, Gb);
            gemm_mfma<<<dim3(cdiv(mc, 256), 8), 256, 0, stream>>>(
                Gb, Wt, x64b + (size_t)q0 * 64, mc, K, 64, cdiv(K / 32, 8) * 32);
        }
    }

    // --- layer 3: 64 -> 3 via P-trick (3-channel P stays cache-resident) ---
    {
        relu_bf16_kernel<<<cdiv(n * 64, 256), 256, 0, stream>>>(x64b, n * 64, hb64);
        wt3_kernel<<<cdiv(192 * 64, 256), 256, 0, stream>>>(w_c3, Wt3);
        gemm_mfma_store<<<dim3(cdiv(n, 64), 3), 256, 0, stream>>>(hb64, Wt3, P3, n, 64, 192);
        conv3_reduce<<<cdiv(n, 4), 256, 0, stream>>>(
            P3, wgt_ff, cl_ff, ff_s, rp_ff, hb64, w_d3, b_d3, n, y3);
    }

    final_kernel<<<cdiv(n * 3, 256), 256, 0, stream>>>(pos, pos2, y3, n, out);
}